// Round 7
// baseline (392.497 us; speedup 1.0000x reference)
//
#include <hip/hip_runtime.h>

#define NB 32
#define NF 256
#define NT 4096
#define PAD_LEN 256

#define TF 16
#define TT 128

// k_march strip width (time cols per wave) and strip count
#define TS 64
#define NSTRIP (NT / TS)   // 64

// f32 gaussian weights: exp(-0.5*c^2)/sum, c=-2..2, sigma=1
#define G0 0.054488684f
#define G1 0.24420134f
#define G2 0.40261995f

// Shared 5-tap blur expression: ONE dag shape used by every kernel so the
// rolling-register path (k_march) and the tile path (k_tail) produce
// bit-identical values. a=minus2-tap, b=plus2-tap, c=minus1, d=plus1, e=center.
__device__ __forceinline__ float blur5(float a, float b, float c, float d, float e) {
    return G0 * (a + b) + G1 * (c + d) + G2 * e;
}
__device__ __forceinline__ float4 blur5v(const float4& a, const float4& b, const float4& c,
                                         const float4& d, const float4& e) {
    return make_float4(blur5(a.x, b.x, c.x, d.x, e.x), blur5(a.y, b.y, c.y, d.y, e.y),
                       blur5(a.z, b.z, c.z, d.z, e.z), blur5(a.w, b.w, c.w, d.w, e.w));
}

#define SW 140
#define SW4 35
#define RS 24   // sS rows: global f0-4 .. f0+19
#define RP 22   // sP rows: global f0-3 .. f0+18
#define RV 18   // sV/sB rows: global f0-1 .. f0+16

#define R1_WORDS (RS * SW)
#define R2_WORDS (RP * SW)

// k_march wave-private stage panel: [256 rows][16 cols], MPAD=16 (NO row padding;
// R5's MPAD=20 made LDS_Block_Size 80KB -> 2 blocks/CU needed exactly 160KB ->
// only 1 block resident (occupancy 10.7%). Conflict-freedom comes from an XOR
// swizzle instead: quad = (row*4 + q) ^ ((row>>2)&7). Write phase: base quads
// (4*lrow+lq) cover all 8 bank-quads, XOR uniform per 16-lane phase. Read phase:
// base const, XOR = lane&7 sweeps all 8. Bijective (XOR bits 0-2, key from bits 4+).
#define MPAD 16

__device__ __forceinline__ int reflectF(int i) {
    i = (i < 0) ? -i : i;
    return (i >= NF) ? (2 * NF - 2 - i) : i;
}
// order-preserving float->uint encoding for atomicMin/Max
__device__ __forceinline__ unsigned encf(float x) {
    unsigned u = __float_as_uint(x);
    return (u & 0x80000000u) ? ~u : (u | 0x80000000u);
}
__device__ __forceinline__ float decf(unsigned e) {
    unsigned u = (e & 0x80000000u) ? (e ^ 0x80000000u) : ~e;
    return __uint_as_float(u);
}

// ws layout: mm[NB][4] @0 ; counts2[NB][NF][32] @1024 ; prefix2 @1024+1MB
#define MM_OFF 0
#define CNT_OFF 1024
#define PFX_OFF (1024 + NB * NF * 32 * 4)

__global__ __launch_bounds__(256) void k_init(float* __restrict__ out, unsigned* __restrict__ mm) {
    int tid = blockIdx.x * 256 + threadIdx.x;
    if (tid < NB * 3 * PAD_LEN) out[tid] = 0.0f;
    if (tid < NB) {
        mm[tid * 4 + 0] = 0xFFFFFFFFu;
        mm[tid * 4 + 1] = 0u;
        mm[tid * 4 + 2] = 0xFFFFFFFFu;
        mm[tid * 4 + 3] = 0u;
    }
}

__global__ __launch_bounds__(256) void k_minmax(const float* __restrict__ spec, unsigned* __restrict__ mm) {
    const int b = blockIdx.y;
    const float4* p = (const float4*)(spec + (size_t)b * NF * NT);
    const int base4 = blockIdx.x * 4096;
    float lmin = __builtin_inff(), lmax = -__builtin_inff();
    for (int i = threadIdx.x; i < 4096; i += 256) {
        float4 v = p[base4 + i];
        lmin = fminf(lmin, fminf(fminf(v.x, v.y), fminf(v.z, v.w)));
        lmax = fmaxf(lmax, fmaxf(fmaxf(v.x, v.y), fmaxf(v.z, v.w)));
    }
    for (int off = 32; off; off >>= 1) {
        lmin = fminf(lmin, __shfl_down(lmin, off));
        lmax = fmaxf(lmax, __shfl_down(lmax, off));
    }
    __shared__ float rmn[4], rmx[4];
    int wave = threadIdx.x >> 6, lane = threadIdx.x & 63;
    if (lane == 0) { rmn[wave] = lmin; rmx[wave] = lmax; }
    __syncthreads();
    if (threadIdx.x == 0) {
        for (int w = 1; w < 4; w++) { lmin = fminf(lmin, rmn[w]); lmax = fmaxf(lmax, rmx[w]); }
        atomicMin(&mm[b * 4 + 0], encf(lmin));
        atomicMax(&mm[b * 4 + 1], encf(lmax));
    }
}

// ---------------------------------------------------------------------------
// k_march: barrier-free rolling-stencil main pass.
// One wave = one 64-col time strip x ALL 256 freq rows (lane l owns rows 4l..4l+3).
// Line-aligned staging: per 16-col group, 4 lanes/row x 16B -> every 64B line
// fetched exactly once. reg->LDS into a wave-private XOR-swizzled panel (16KB);
// LDS->reg in compute layout. GLOAD(j+1) issues before group j's march steps.
// ---------------------------------------------------------------------------

template<int J> __device__ __forceinline__ float getj(const float4& v) {
    if constexpr (J == 0) return v.x;
    else if constexpr (J == 1) return v.y;
    else if constexpr (J == 2) return v.z;
    else return v.w;
}

template<bool DP, bool DH, bool DQ, int J>
__device__ __forceinline__ void march_step(
    const float4& r0, const float4& r1, const float4& r2, const float4& r3,
    float4& Sa, float4& Sb, float4& Sc,
    float4& V0, float4& V1, float4& V2, float4& V3, float4& V4,
    float4& Bm, float4& Bc, float4& Bp,
    int& c0, int& c1, int& c2, int& c3,
    float& lmin, float& lmax,
    const int lane, const int sid, const float mn, const float rinv, const int hb)
{
    const float NEGF = -__builtin_inff();
    float4 X = make_float4(getj<J>(r0), getj<J>(r1), getj<J>(r2), getj<J>(r3));
    Sa = Sb; Sb = Sc; Sc = X;
    if constexpr (DP) {
        // p1 at col u = t-1: x = Sb (center col), left = Sa, right = Sc,
        // up/down = freq-neighbors (in-quad + lane shuffles, -inf at image rows)
        float up0 = __shfl_up(Sb.w, 1);
        float dn3 = __shfl_down(Sb.x, 1);
        if (lane == 0)  up0 = NEGF;
        if (lane == 63) dn3 = NEGF;
        float4 P;
        { const float x = Sb.x; const bool pk = (x >= Sa.x) && (x >= Sc.x) && (x >= up0)  && (x >= Sb.y); P.x = pk ? (x - mn) * rinv : 0.0f; }
        { const float x = Sb.y; const bool pk = (x >= Sa.y) && (x >= Sc.y) && (x >= Sb.x) && (x >= Sb.z); P.y = pk ? (x - mn) * rinv : 0.0f; }
        { const float x = Sb.z; const bool pk = (x >= Sa.z) && (x >= Sc.z) && (x >= Sb.y) && (x >= Sb.w); P.z = pk ? (x - mn) * rinv : 0.0f; }
        { const float x = Sb.w; const bool pk = (x >= Sa.w) && (x >= Sc.w) && (x >= Sb.z) && (x >= dn3); P.w = pk ? (x - mn) * rinv : 0.0f; }
        // vblur (freq 5-tap) at col u; reflectF at rows 0,1 (lane 0) / 254,255 (lane 63)
        const float pzm = __shfl_up(P.z, 1);     // row 4l-2
        const float pwm = __shfl_up(P.w, 1);     // row 4l-1
        const float pxp = __shfl_down(P.x, 1);   // row 4l+4
        const float pyp = __shfl_down(P.y, 1);   // row 4l+5
        float4 Vn;
        Vn.x = blur5(pzm, P.z, pwm, P.y, P.x);
        Vn.y = blur5(pwm, P.w, P.x, P.z, P.y);
        Vn.z = blur5(P.x, pxp, P.y, P.w, P.z);
        Vn.w = blur5(P.y, pyp, P.z, pxp, P.w);
        if (lane == 0)  { Vn.x = blur5(P.z, P.z, P.y, P.y, P.x);   // f=0: taps 2,1,0,1,2
                          Vn.y = blur5(P.y, P.w, P.x, P.z, P.y); } // f=1: taps 1,0,1,2,3
        if (lane == 63) { Vn.z = blur5(P.x, P.z, P.y, P.w, P.z);   // f=254: taps 252,253,254,255,254
                          Vn.w = blur5(P.y, P.y, P.z, P.z, P.w); } // f=255: taps 253,254,255,254,253
        V0 = V1; V1 = V2; V2 = V3; V3 = V4; V4 = Vn;
    }
    if constexpr (DH) {
        // hblur (time 5-tap) at col h = hb + J; ring V0..V4 = cols h-2..h+2.
        const int h = hb + J;
        float4 Bn;
        if ((unsigned)h < (unsigned)NT) {
            Bn = blur5v(V0, V4, V1, V3, V2);
            if (sid == 0) {
                if (h == 0)      Bn = blur5v(V4, V4, V3, V3, V2);  // taps 2,1,0,1,2
                else if (h == 1) Bn = blur5v(V2, V4, V1, V3, V2);  // taps 1,0,1,2,3
            }
            if (sid == NSTRIP - 1) {
                if (h == NT - 2)      Bn = blur5v(V0, V2, V1, V3, V2);  // taps 4092,4093,4094,4095,4094
                else if (h == NT - 1) Bn = blur5v(V0, V0, V1, V1, V2);  // taps 4093,4094,4095,4094,4093
            }
        } else {
            Bn = make_float4(NEGF, NEGF, NEGF, NEGF);
        }
        Bm = Bc; Bc = Bp; Bp = Bn;
    }
    if constexpr (DQ) {
        // peak2 + count at col q = h-1: x = Bc, left = Bm, right = Bp, freq via shuffles
        float u0 = __shfl_up(Bc.w, 1);
        float d3 = __shfl_down(Bc.x, 1);
        if (lane == 0)  u0 = NEGF;
        if (lane == 63) d3 = NEGF;
        { const float x = Bc.x; const bool pk = (x >= Bm.x) && (x >= Bp.x) && (x >= u0)   && (x >= Bc.y); c0 += (pk && (x > 0.0f)) ? 1 : 0; }
        { const float x = Bc.y; const bool pk = (x >= Bm.y) && (x >= Bp.y) && (x >= Bc.x) && (x >= Bc.z); c1 += (pk && (x > 0.0f)) ? 1 : 0; }
        { const float x = Bc.z; const bool pk = (x >= Bm.z) && (x >= Bp.z) && (x >= Bc.y) && (x >= Bc.w); c2 += (pk && (x > 0.0f)) ? 1 : 0; }
        { const float x = Bc.w; const bool pk = (x >= Bm.w) && (x >= Bp.w) && (x >= Bc.z) && (x >= d3); c3 += (pk && (x > 0.0f)) ? 1 : 0; }
        lmin = fminf(lmin, fminf(fminf(Bc.x, Bc.y), fminf(Bc.z, Bc.w)));
        lmax = fmaxf(lmax, fmaxf(fmaxf(Bc.x, Bc.y), fmaxf(Bc.z, Bc.w)));
    }
}

__global__ __launch_bounds__(256) void k_march(const float* __restrict__ spec,
                                               unsigned* __restrict__ mm,
                                               int* __restrict__ counts2) {
    const int b = blockIdx.y;
    const int lane = threadIdx.x & 63;
    const int wv = threadIdx.x >> 6;
    const int sid = blockIdx.x * 4 + wv;
    const int T0 = sid * TS;

    const float mn = decf(mm[b * 4 + 0]);
    const float mx = decf(mm[b * 4 + 1]);
    const float rinv = 1.0f / (mx - mn);

    const float NEGF = -__builtin_inff();
    const float4 NEG4 = make_float4(NEGF, NEGF, NEGF, NEGF);

    // wave-private stage panel: 256 rows x 16 cols, XOR-swizzled (group j covers
    // cols T0-16+16j..+15). 16KB/wave -> 64KB/block -> 2 blocks/CU (the R5 fix).
    __shared__ __align__(16) float sStage[4][256 * MPAD];
    float* myS = sStage[wv];

    const int lrow = lane >> 2;   // 0..15: row within 16-row slab
    const int lq = lane & 3;      // which 16B quad of the 64B line
    const float* gb = spec + (size_t)b * NF * NT;

    float4 R[16];   // staging registers: one full 16-col group (256 rows)
    float4 A[4];    // compute registers: rows 4l..4l+3, one 4-col set

#define GLOAD(J) do {                                                           \
    const int tg = T0 - 16 + 16 * (J);                                          \
    if ((unsigned)tg < (unsigned)NT) {                                          \
        const float* gp = gb + (size_t)lrow * NT + tg + 4 * lq;                 \
        _Pragma("unroll")                                                       \
        for (int i = 0; i < 16; ++i)                                            \
            R[i] = *(const float4*)(gp + (size_t)(16 * i) * NT);                \
    } else {                                                                    \
        _Pragma("unroll")                                                       \
        for (int i = 0; i < 16; ++i) R[i] = NEG4;                               \
    }                                                                           \
} while (0)

#define SWRITE() do {                                                           \
    _Pragma("unroll")                                                           \
    for (int i = 0; i < 16; ++i) {                                              \
        const int row_ = 16 * i + lrow;                                         \
        const int q_ = (row_ * 4 + lq) ^ ((row_ >> 2) & 7);                     \
        *(float4*)(myS + 4 * q_) = R[i];                                        \
    }                                                                           \
} while (0)

#define SREAD(C) do {                                                           \
    _Pragma("unroll")                                                           \
    for (int j = 0; j < 4; ++j) {                                               \
        const int row_ = 4 * lane + j;                                          \
        const int q_ = (row_ * 4 + ((C) >> 2)) ^ ((row_ >> 2) & 7);             \
        A[j] = *(const float4*)(myS + 4 * q_);                                  \
    }                                                                           \
} while (0)

    float4 Sa = NEG4, Sb = NEG4, Sc = NEG4;
    float4 V0 = NEG4, V1 = NEG4, V2 = NEG4, V3 = NEG4, V4 = NEG4;
    float4 Bm = NEG4, Bc = NEG4, Bp = NEG4;
    int c0 = 0, c1 = 0, c2 = 0, c3 = 0;
    float lmin = __builtin_inff(), lmax = NEGF;

#define MARGS Sa, Sb, Sc, V0, V1, V2, V3, V4, Bm, Bc, Bp, c0, c1, c2, c3, lmin, lmax, lane, sid, mn, rinv

#define SET_FULL(C, HB) do { SREAD(C); const int hb_ = (HB);                    \
    march_step<true, true, true, 0>(A[0], A[1], A[2], A[3], MARGS, hb_);        \
    march_step<true, true, true, 1>(A[0], A[1], A[2], A[3], MARGS, hb_);        \
    march_step<true, true, true, 2>(A[0], A[1], A[2], A[3], MARGS, hb_);        \
    march_step<true, true, true, 3>(A[0], A[1], A[2], A[3], MARGS, hb_); } while (0)

    GLOAD(0);
    SWRITE();
    GLOAD(1);
    // set 0 (cols T0-4..T0-1, panel quad 3 of group 0): ring fill + first p1
    SREAD(12);
    march_step<false, false, false, 0>(A[0], A[1], A[2], A[3], MARGS, 0);
    march_step<false, false, false, 1>(A[0], A[1], A[2], A[3], MARGS, 0);
    march_step<true,  false, false, 2>(A[0], A[1], A[2], A[3], MARGS, 0);
    march_step<true,  false, false, 3>(A[0], A[1], A[2], A[3], MARGS, 0);
    SWRITE();
    GLOAD(2);
    // set 1 (cols T0..T0+3): p1; hblur starts on last two (h = T0-1, T0)
    {
        const int hb_ = T0 - 3;
        SREAD(0);
        march_step<true, false, false, 0>(A[0], A[1], A[2], A[3], MARGS, hb_);
        march_step<true, false, false, 1>(A[0], A[1], A[2], A[3], MARGS, hb_);
        march_step<true, true,  false, 2>(A[0], A[1], A[2], A[3], MARGS, hb_);
        march_step<true, true,  false, 3>(A[0], A[1], A[2], A[3], MARGS, hb_);
    }
    // sets 2..17: full pipeline (hb = T0-7+4s)
    SET_FULL(4,  T0 + 1);
    SET_FULL(8,  T0 + 5);
    SET_FULL(12, T0 + 9);
    SWRITE(); GLOAD(3);
    SET_FULL(0,  T0 + 13); SET_FULL(4,  T0 + 17); SET_FULL(8,  T0 + 21); SET_FULL(12, T0 + 25);
    SWRITE(); GLOAD(4);
    SET_FULL(0,  T0 + 29); SET_FULL(4,  T0 + 33); SET_FULL(8,  T0 + 37); SET_FULL(12, T0 + 41);
    SWRITE(); GLOAD(5);
    SET_FULL(0,  T0 + 45); SET_FULL(4,  T0 + 49); SET_FULL(8,  T0 + 53); SET_FULL(12, T0 + 57);
    SWRITE();
    SET_FULL(0,  T0 + 61);

#undef SET_FULL
#undef GLOAD
#undef SWRITE
#undef SREAD
#undef MARGS

    // partner-wave combine (waves 2k,2k+1 share one 128-col chunk) -> plain stores
    int* sc = (int*)&sStage[0][0];
    __syncthreads();
    sc[threadIdx.x * 4 + 0] = c0;
    sc[threadIdx.x * 4 + 1] = c1;
    sc[threadIdx.x * 4 + 2] = c2;
    sc[threadIdx.x * 4 + 3] = c3;
    __syncthreads();
    if ((wv & 1) == 0) {
        const int p = (threadIdx.x + 64) * 4;
        const int cc = sid >> 1;
        const int fr = 4 * lane;
        counts2[(b * NF + fr + 0) * 32 + cc] = c0 + sc[p + 0];
        counts2[(b * NF + fr + 1) * 32 + cc] = c1 + sc[p + 1];
        counts2[(b * NF + fr + 2) * 32 + cc] = c2 + sc[p + 2];
        counts2[(b * NF + fr + 3) * 32 + cc] = c3 + sc[p + 3];
    }

    for (int off = 32; off; off >>= 1) {
        lmin = fminf(lmin, __shfl_down(lmin, off));
        lmax = fmaxf(lmax, __shfl_down(lmax, off));
    }
    if (lane == 0) {
        atomicMin(&mm[b * 4 + 2], encf(lmin));
        atomicMax(&mm[b * 4 + 3], encf(lmax));
    }
}

// ---------------------------------------------------------------------------
// Tile path (verified): used inside k_tail for the few active tiles.
// ---------------------------------------------------------------------------
__device__ __forceinline__ void blur_tile(const float* __restrict__ sb_base,
                                          int f0, int t0, float mn, float rinv,
                                          float* sR1, float* sR2, int tid,
                                          bool f_lo, bool f_hi, bool t_lo, bool t_hi) {
    const float NEG = -__builtin_inff();
    float* sS = sR1;
    float* sV = sR1;   // overlays sS
    float* sB = sR2;   // overlays sP
    float4* sS4 = (float4*)sR1;
    float4* sP4 = (float4*)sR2;
    float4* sV4 = (float4*)sR1;
    float4* sB4 = (float4*)sR2;

    const bool f_edge = f_lo || f_hi;
    const bool t_edge = t_lo || t_hi;
    const int lane = tid & 63;

    // Phase A: stage spec rows f0-4..f0+19, slots 0..135 (cols t0-4..t0+131).
    if (!f_edge && !t_edge) {
        const float4* gp = (const float4*)(sb_base + (size_t)(f0 - 4) * NT + (t0 - 4));
        for (int i = tid; i < RS * 34; i += 256) {
            int r = i / 34, c = i - r * 34;
            sS4[r * SW4 + c] = gp[r * (NT / 4) + c];
        }
    } else {
        for (int i = tid; i < RS * 34; i += 256) {
            int r = i / 34, c = i - r * 34;
            int gf = f0 - 4 + r;
            int gc0 = t0 - 4 + 4 * c;
            float4 v = make_float4(NEG, NEG, NEG, NEG);
            if ((unsigned)gf < NF && (unsigned)gc0 < NT)
                v = *(const float4*)(sb_base + (size_t)gf * NT + gc0);
            sS4[r * SW4 + c] = v;
        }
    }
    __syncthreads();

    // Phase B: p1 = isPeak(spec) ? (spec-mn)*rinv : 0 ; rows 0..21 (f0-3..f0+18).
    for (int i = tid; i < RP * 34; i += 256) {
        int r = i / 34, g = i - r * 34;
        const float4 c4 = sS4[(r + 1) * SW4 + g];
        const float4 u4 = sS4[r * SW4 + g];
        const float4 d4 = sS4[(r + 2) * SW4 + g];
        float lm = __shfl_up(c4.w, 1);
        float rp = __shfl_down(c4.x, 1);
        if (lane == 0 && g > 0)   lm = sS[(r + 1) * SW + 4 * g - 1];
        if (lane == 63 && g < 33) rp = sS[(r + 1) * SW + 4 * g + 4];
        float4 o;
        o.x = (c4.x >= lm   && c4.x >= c4.y && c4.x >= u4.x && c4.x >= d4.x) ? (c4.x - mn) * rinv : 0.0f;
        o.y = (c4.y >= c4.x && c4.y >= c4.z && c4.y >= u4.y && c4.y >= d4.y) ? (c4.y - mn) * rinv : 0.0f;
        o.z = (c4.z >= c4.y && c4.z >= c4.w && c4.z >= u4.z && c4.z >= d4.z) ? (c4.z - mn) * rinv : 0.0f;
        o.w = (c4.w >= c4.z && c4.w >= rp   && c4.w >= u4.w && c4.w >= d4.w) ? (c4.w - mn) * rinv : 0.0f;
        if (g == 0) o.x = 0.0f;
        if (g == 33) o.w = 0.0f;
        sP4[r * SW4 + g] = o;
    }
    __syncthreads();

    // Phase C: vertical (freq) 5-tap -> sV rows 0..17 (f0-1..f0+16).
    if (!f_edge) {
        for (int i = tid; i < RV * 34; i += 256) {
            int r = i / 34, g = i - r * 34;
            const float4 p0 = sP4[r * SW4 + g];
            const float4 p1 = sP4[(r + 1) * SW4 + g];
            const float4 p2 = sP4[(r + 2) * SW4 + g];
            const float4 p3 = sP4[(r + 3) * SW4 + g];
            const float4 p4 = sP4[(r + 4) * SW4 + g];
            sV4[r * SW4 + g] = blur5v(p0, p4, p1, p3, p2);
        }
    } else {
        for (int i = tid; i < RV * 34; i += 256) {
            int r = i / 34, g = i - r * 34;
            const int gf = f0 - 1 + r;
            const int r0 = reflectF(gf - 2) - (f0 - 3);
            const int r1 = reflectF(gf - 1) - (f0 - 3);
            const int r2 = gf - (f0 - 3);
            const int r3 = reflectF(gf + 1) - (f0 - 3);
            const int r4 = reflectF(gf + 2) - (f0 - 3);
            const float4 p0 = sP4[r0 * SW4 + g];
            const float4 p1 = sP4[r1 * SW4 + g];
            const float4 p2 = sP4[r2 * SW4 + g];
            const float4 p3 = sP4[r3 * SW4 + g];
            const float4 p4 = sP4[r4 * SW4 + g];
            sV4[r * SW4 + g] = blur5v(p0, p4, p1, p3, p2);
        }
    }
    __syncthreads();

    // Phase D: horizontal (time) 5-tap -> sB rows 0..17, slots 3..132.
    for (int i = tid; i < RV * 32; i += 256) {
        int r = i >> 5, g = 1 + (i & 31);
        const float4 A = sV4[r * SW4 + g - 1];
        const float4 B = sV4[r * SW4 + g];
        const float4 C = sV4[r * SW4 + g + 1];
        float4 o;
        o.x = blur5(A.z, B.z, A.w, B.y, B.x);
        o.y = blur5(A.w, B.w, B.x, B.z, B.y);
        o.z = blur5(B.x, C.x, B.y, B.w, B.z);
        o.w = blur5(B.y, C.y, B.z, C.x, B.w);
        if (t_lo && g == 1) {
            o.x = blur5(B.z, B.z, B.y, B.y, B.x);
            o.y = blur5(B.y, B.w, B.x, B.z, B.y);
        }
        if (t_hi && g == 32) {
            o.z = blur5(B.x, B.z, B.y, B.w, B.z);
            o.w = blur5(B.y, B.y, B.z, B.z, B.w);
        }
        if ((f_lo && r == 0) || (f_hi && r == 17)) o = make_float4(NEG, NEG, NEG, NEG);
        sB4[r * SW4 + g] = o;
    }
    for (int i = tid; i < RV * 2; i += 256) {
        int r = i >> 1;
        int hi = i & 1;
        int s = hi ? 132 : 3;
        const float* vr = sV + r * SW;
        float v = blur5(vr[s - 2], vr[s + 2], vr[s - 1], vr[s + 1], vr[s]);
        if ((hi ? t_hi : t_lo) || (f_lo && r == 0) || (f_hi && r == 17)) v = NEG;
        sB[r * SW + s] = v;
    }
    __syncthreads();
}

struct Win8 {
    float c[8], l[8], rr[8], u[8], d[8];
};
__device__ __forceinline__ void load_win8(const float4* sB4, int r, int m, Win8& w) {
    const int g = 1 + 2 * m;
    const float4 Cm = sB4[(r + 1) * SW4 + g - 1];
    const float4 C0 = sB4[(r + 1) * SW4 + g];
    const float4 C1 = sB4[(r + 1) * SW4 + g + 1];
    const float4 C2 = sB4[(r + 1) * SW4 + g + 2];
    const float4 U0 = sB4[r * SW4 + g];
    const float4 U1 = sB4[r * SW4 + g + 1];
    const float4 D0 = sB4[(r + 2) * SW4 + g];
    const float4 D1 = sB4[(r + 2) * SW4 + g + 1];
    w.c[0] = C0.x; w.c[1] = C0.y; w.c[2] = C0.z; w.c[3] = C0.w;
    w.c[4] = C1.x; w.c[5] = C1.y; w.c[6] = C1.z; w.c[7] = C1.w;
    w.l[0] = Cm.w; w.l[1] = C0.x; w.l[2] = C0.y; w.l[3] = C0.z;
    w.l[4] = C0.w; w.l[5] = C1.x; w.l[6] = C1.y; w.l[7] = C1.z;
    w.rr[0] = C0.y; w.rr[1] = C0.z; w.rr[2] = C0.w; w.rr[3] = C1.x;
    w.rr[4] = C1.y; w.rr[5] = C1.z; w.rr[6] = C1.w; w.rr[7] = C2.x;
    w.u[0] = U0.x; w.u[1] = U0.y; w.u[2] = U0.z; w.u[3] = U0.w;
    w.u[4] = U1.x; w.u[5] = U1.y; w.u[6] = U1.z; w.u[7] = U1.w;
    w.d[0] = D0.x; w.d[1] = D0.y; w.d[2] = D0.z; w.d[3] = D0.w;
    w.d[4] = D1.x; w.d[5] = D1.y; w.d[6] = D1.z; w.d[7] = D1.w;
}

// ---------------------------------------------------------------------------
// k_tail: one block per batch. (1) optional pathological recount (mn2 != 0),
// (2) in-block prefix scan over [NF][32], (3) loop tiles row-major, break at
// the PAD_LEN cap (prefix monotone), skip zero-count tiles, blur+extract.
// Replaces the old k_prefix + 16384-block k_extract launch.
// ---------------------------------------------------------------------------
__global__ __launch_bounds__(256) void k_tail(const float* __restrict__ spec,
                                              unsigned* __restrict__ mm,
                                              int* __restrict__ counts2,
                                              int* __restrict__ prefix2,
                                              float* __restrict__ out) {
    const int b = blockIdx.x;
    const int tid = threadIdx.x;
    __shared__ __align__(16) float sR1[R1_WORDS];
    __shared__ __align__(16) float sR2[R2_WORDS];
    const float4* sB4 = (const float4*)sR2;

    const float mn = decf(mm[b * 4 + 0]);
    const float mx = decf(mm[b * 4 + 1]);
    const float rinv = 1.0f / (mx - mn);
    const float mn2 = decf(mm[b * 4 + 2]);
    const float mx2 = decf(mm[b * 4 + 3]);
    const float rinv2 = 1.0f / (mx2 - mn2);
    const float* sb_base = spec + (size_t)b * NF * NT;

    if (mn2 != 0.0f) {
        // pathological-input slow path: recount every tile with threshold x > mn2
        int* pcnt = (int*)sR1;
        for (int ty = 0; ty < NF / TF; ++ty)
        for (int tx = 0; tx < NT / TT; ++tx) {
            blur_tile(sb_base, ty * TF, tx * TT, mn, rinv, sR1, sR2, tid,
                      ty == 0, ty == NF / TF - 1, tx == 0, tx == NT / TT - 1);
            const int r = tid & 15, m = tid >> 4;
            Win8 w;
            load_win8(sB4, r, m, w);
            int cnt = 0;
#pragma unroll
            for (int k = 0; k < 8; k++) {
                float x = w.c[k];
                bool pk = (x >= w.l[k]) && (x >= w.rr[k]) && (x >= w.u[k]) && (x >= w.d[k]);
                cnt += (pk && (x > mn2)) ? 1 : 0;
            }
            (void)m;
            const int lane = tid & 63, wvv = tid >> 6;
            int cs = cnt;
            cs += __shfl_down(cs, 32);
            cs += __shfl_down(cs, 16);
            if (lane < 16) pcnt[wvv * 16 + lane] = cs;
            __syncthreads();
            if (tid < 16)
                counts2[(b * NF + ty * TF + tid) * 32 + tx] =
                    pcnt[tid] + pcnt[16 + tid] + pcnt[32 + tid] + pcnt[48 + tid];
            __syncthreads();
        }
    }

    // prefix over [NF rows][32 chunks], row-major
    const int* cb = counts2 + b * NF * 32;
    int* pb = prefix2 + b * NF * 32;
    {
        int local[32];
        int s = 0;
        for (int c = 0; c < 32; c++) {
            local[c] = cb[tid * 32 + c];
            s += local[c];
        }
        __shared__ int tot[256];
        tot[tid] = s;
        __syncthreads();
        for (int off = 1; off < 256; off <<= 1) {
            int v = (tid >= off) ? tot[tid - off] : 0;
            __syncthreads();
            tot[tid] += v;
            __syncthreads();
        }
        int run = tot[tid] - s;
        for (int c = 0; c < 32; c++) {
            pb[tid * 32 + c] = run;
            run += local[c];
        }
    }

    // tile loop (row-major in (ty, tx) == row-major tile-start prefix order)
    __shared__ int sInfo[2];
    __shared__ int wtot[4][16];
    for (int t = 0; t < (NF / TF) * (NT / TT); ++t) {
        const int ty = t >> 5, tx = t & 31;
        const int f0 = ty * TF, t0 = tx * TT;
        __syncthreads();   // protects sInfo/wtot reuse and pb visibility
        if (tid == 0) sInfo[0] = pb[f0 * 32 + tx];
        int tc = 0;
        if (tid < 16) tc = cb[(f0 + tid) * 32 + tx];
        tc += __shfl_down(tc, 8, 16);
        tc += __shfl_down(tc, 4, 16);
        tc += __shfl_down(tc, 2, 16);
        tc += __shfl_down(tc, 1, 16);
        if (tid == 0) sInfo[1] = tc;
        __syncthreads();
        if (sInfo[0] >= PAD_LEN) break;   // monotone -> no later tile can write
        if (sInfo[1] == 0) continue;      // no peaks in this tile

        const bool f_lo = (ty == 0), f_hi = (ty == NF / TF - 1);
        const bool t_lo = (tx == 0), t_hi = (tx == NT / TT - 1);
        blur_tile(sb_base, f0, t0, mn, rinv, sR1, sR2, tid, f_lo, f_hi, t_lo, t_hi);

        const int r = tid & 15, m = tid >> 4;
        const int gf = f0 + r;
        const int base = pb[gf * 32 + tx];
        Win8 w;
        load_win8(sB4, r, m, w);
        bool pos[8];
        int mycnt = 0;
#pragma unroll
        for (int k = 0; k < 8; k++) {
            float x = w.c[k];
            pos[k] = (x >= w.l[k]) && (x >= w.rr[k]) && (x >= w.u[k]) && (x >= w.d[k]) && (x > mn2);
            mycnt += pos[k] ? 1 : 0;
        }
        // inclusive scan over m = wv*4 + p
        const int lane = tid & 63, wv = tid >> 6, p = (tid >> 4) & 3;
        int s = mycnt;
        int t1 = __shfl_up(s, 16); if (p >= 1) s += t1;
        int t2 = __shfl_up(s, 32); if (p >= 2) s += t2;
        if (p == 3) wtot[wv][lane & 15] = s;
        __syncthreads();
        int woff = 0;
        for (int w2 = 0; w2 < wv; ++w2) woff += wtot[w2][r];
        int rank = base + woff + (s - mycnt);
#pragma unroll
        for (int k = 0; k < 8; k++) {
            if (pos[k]) {
                if (rank < PAD_LEN) {
                    int gc = t0 + 8 * m + k;
                    out[b * 768 + rank]       = (float)gf * (1.0f / 256.0f);
                    out[b * 768 + 256 + rank] = (float)gc * (1.0f / 4096.0f);
                    out[b * 768 + 512 + rank] = (w.c[k] - mn2) * rinv2;
                }
                rank++;
            }
        }
    }
}

extern "C" void kernel_launch(void* const* d_in, const int* in_sizes, int n_in,
                              void* d_out, int out_size, void* d_ws, size_t ws_size,
                              hipStream_t stream) {
    const float* spec = (const float*)d_in[0];
    float* out = (float*)d_out;
    unsigned* mm = (unsigned*)((char*)d_ws + MM_OFF);
    int* counts2 = (int*)((char*)d_ws + CNT_OFF);
    int* prefix2 = (int*)((char*)d_ws + PFX_OFF);

    k_init<<<96, 256, 0, stream>>>(out, mm);
    k_minmax<<<dim3(64, NB), 256, 0, stream>>>(spec, mm);
    k_march<<<dim3(NSTRIP / 4, NB), 256, 0, stream>>>(spec, mm, counts2);
    k_tail<<<NB, 256, 0, stream>>>(spec, mm, counts2, prefix2, out);
}

// Round 9
// 362.706 us; speedup vs baseline: 1.0821x; 1.0821x over previous
//
#include <hip/hip_runtime.h>

#define NB 32
#define NF 256
#define NT 4096
#define PAD_LEN 256

#define TF 16
#define TT 128

// k_march strip width (time cols per wave) and strip count.
// R8: TS 64->32. The R7 grid (512 blocks = 2048 waves) supplied only 2 waves/SIMD
// chip-wide -- occupancy could never exceed what we measured regardless of LDS/VGPR.
// 128 strips -> 1024 blocks -> 4 waves/SIMD available.
#define TS 32
#define NSTRIP (NT / TS)   // 128

// f32 gaussian weights: exp(-0.5*c^2)/sum, c=-2..2, sigma=1
#define G0 0.054488684f
#define G1 0.24420134f
#define G2 0.40261995f

__device__ __forceinline__ float blur5(float a, float b, float c, float d, float e) {
    return G0 * (a + b) + G1 * (c + d) + G2 * e;
}
__device__ __forceinline__ float4 blur5v(const float4& a, const float4& b, const float4& c,
                                         const float4& d, const float4& e) {
    return make_float4(blur5(a.x, b.x, c.x, d.x, e.x), blur5(a.y, b.y, c.y, d.y, e.y),
                       blur5(a.z, b.z, c.z, d.z, e.z), blur5(a.w, b.w, c.w, d.w, e.w));
}

#define SW 140
#define SW4 35
#define RS 24   // sS rows: global f0-4 .. f0+19
#define RP 22   // sP rows: global f0-3 .. f0+18
#define RV 18   // sV/sB rows: global f0-1 .. f0+16

#define R1_WORDS (RS * SW)
#define R2_WORDS (RP * SW)

__device__ __forceinline__ int reflectF(int i) {
    i = (i < 0) ? -i : i;
    return (i >= NF) ? (2 * NF - 2 - i) : i;
}
__device__ __forceinline__ unsigned encf(float x) {
    unsigned u = __float_as_uint(x);
    return (u & 0x80000000u) ? ~u : (u | 0x80000000u);
}
__device__ __forceinline__ float decf(unsigned e) {
    unsigned u = (e & 0x80000000u) ? (e ^ 0x80000000u) : ~e;
    return __uint_as_float(u);
}

// ws layout: mm[NB][4] @0 ; counts2[NB][NF][32] @1024 ; prefix2 @1024+1MB
#define MM_OFF 0
#define CNT_OFF 1024
#define PFX_OFF (1024 + NB * NF * 32 * 4)

__global__ __launch_bounds__(256) void k_init(float* __restrict__ out, unsigned* __restrict__ mm) {
    int tid = blockIdx.x * 256 + threadIdx.x;
    if (tid < NB * 3 * PAD_LEN) out[tid] = 0.0f;
    if (tid < NB) {
        mm[tid * 4 + 0] = 0xFFFFFFFFu;
        mm[tid * 4 + 1] = 0u;
        mm[tid * 4 + 2] = 0xFFFFFFFFu;
        mm[tid * 4 + 3] = 0u;
    }
}

__global__ __launch_bounds__(256) void k_minmax(const float* __restrict__ spec, unsigned* __restrict__ mm) {
    const int b = blockIdx.y;
    const float4* p = (const float4*)(spec + (size_t)b * NF * NT);
    const int base4 = blockIdx.x * 4096;
    float lmin = __builtin_inff(), lmax = -__builtin_inff();
    for (int i = threadIdx.x; i < 4096; i += 256) {
        float4 v = p[base4 + i];
        lmin = fminf(lmin, fminf(fminf(v.x, v.y), fminf(v.z, v.w)));
        lmax = fmaxf(lmax, fmaxf(fmaxf(v.x, v.y), fmaxf(v.z, v.w)));
    }
    for (int off = 32; off; off >>= 1) {
        lmin = fminf(lmin, __shfl_down(lmin, off));
        lmax = fmaxf(lmax, __shfl_down(lmax, off));
    }
    __shared__ float rmn[4], rmx[4];
    int wave = threadIdx.x >> 6, lane = threadIdx.x & 63;
    if (lane == 0) { rmn[wave] = lmin; rmx[wave] = lmax; }
    __syncthreads();
    if (threadIdx.x == 0) {
        for (int w = 1; w < 4; w++) { lmin = fminf(lmin, rmn[w]); lmax = fmaxf(lmax, rmx[w]); }
        atomicMin(&mm[b * 4 + 0], encf(lmin));
        atomicMax(&mm[b * 4 + 1], encf(lmax));
    }
}

// ---------------------------------------------------------------------------
// k_march: barrier-free rolling-stencil main pass.
// One wave = one 32-col strip x all 256 freq rows (lane l owns rows 4l..4l+3).
// R8 staging: 8-col groups, R[8] regs (2 lanes/row x 16B, coalesced 32B/row),
// single 8KB/wave LDS panel (32KB/block). T14 overlap: GLOAD(G+1) issued before
// group G's compute; ds_write waits are compiler-counted vmcnt on R deps.
// Panel swizzle: slot = (row*2+q) ^ ((row>>2)&7); write banks (l&7)^((l>>3)&1),
// read banks (2j+qc)^(l&7) -> both 2-way = free.
// ---------------------------------------------------------------------------

template<int J> __device__ __forceinline__ float getj(const float4& v) {
    if constexpr (J == 0) return v.x;
    else if constexpr (J == 1) return v.y;
    else if constexpr (J == 2) return v.z;
    else return v.w;
}

template<bool DP, bool DH, bool DQ, int J>
__device__ __forceinline__ void march_step(
    const float4& r0, const float4& r1, const float4& r2, const float4& r3,
    float4& Sa, float4& Sb, float4& Sc,
    float4& V0, float4& V1, float4& V2, float4& V3, float4& V4,
    float4& Bm, float4& Bc, float4& Bp,
    int& c0, int& c1, int& c2, int& c3,
    float& lmin, float& lmax,
    const int lane, const int sid, const float mn, const float rinv, const int hb)
{
    const float NEGF = -__builtin_inff();
    float4 X = make_float4(getj<J>(r0), getj<J>(r1), getj<J>(r2), getj<J>(r3));
    Sa = Sb; Sb = Sc; Sc = X;
    if constexpr (DP) {
        float up0 = __shfl_up(Sb.w, 1);
        float dn3 = __shfl_down(Sb.x, 1);
        if (lane == 0)  up0 = NEGF;
        if (lane == 63) dn3 = NEGF;
        float4 P;
        { const float x = Sb.x; const bool pk = (x >= Sa.x) && (x >= Sc.x) && (x >= up0)  && (x >= Sb.y); P.x = pk ? (x - mn) * rinv : 0.0f; }
        { const float x = Sb.y; const bool pk = (x >= Sa.y) && (x >= Sc.y) && (x >= Sb.x) && (x >= Sb.z); P.y = pk ? (x - mn) * rinv : 0.0f; }
        { const float x = Sb.z; const bool pk = (x >= Sa.z) && (x >= Sc.z) && (x >= Sb.y) && (x >= Sb.w); P.z = pk ? (x - mn) * rinv : 0.0f; }
        { const float x = Sb.w; const bool pk = (x >= Sa.w) && (x >= Sc.w) && (x >= Sb.z) && (x >= dn3); P.w = pk ? (x - mn) * rinv : 0.0f; }
        const float pzm = __shfl_up(P.z, 1);     // row 4l-2
        const float pwm = __shfl_up(P.w, 1);     // row 4l-1
        const float pxp = __shfl_down(P.x, 1);   // row 4l+4
        const float pyp = __shfl_down(P.y, 1);   // row 4l+5
        float4 Vn;
        Vn.x = blur5(pzm, P.z, pwm, P.y, P.x);
        Vn.y = blur5(pwm, P.w, P.x, P.z, P.y);
        Vn.z = blur5(P.x, pxp, P.y, P.w, P.z);
        Vn.w = blur5(P.y, pyp, P.z, pxp, P.w);
        if (lane == 0)  { Vn.x = blur5(P.z, P.z, P.y, P.y, P.x);
                          Vn.y = blur5(P.y, P.w, P.x, P.z, P.y); }
        if (lane == 63) { Vn.z = blur5(P.x, P.z, P.y, P.w, P.z);
                          Vn.w = blur5(P.y, P.y, P.z, P.z, P.w); }
        V0 = V1; V1 = V2; V2 = V3; V3 = V4; V4 = Vn;
    }
    if constexpr (DH) {
        const int h = hb + J;
        float4 Bn;
        if ((unsigned)h < (unsigned)NT) {
            Bn = blur5v(V0, V4, V1, V3, V2);
            if (sid == 0) {
                if (h == 0)      Bn = blur5v(V4, V4, V3, V3, V2);
                else if (h == 1) Bn = blur5v(V2, V4, V1, V3, V2);
            }
            if (sid == NSTRIP - 1) {
                if (h == NT - 2)      Bn = blur5v(V0, V2, V1, V3, V2);
                else if (h == NT - 1) Bn = blur5v(V0, V0, V1, V1, V2);
            }
        } else {
            Bn = make_float4(NEGF, NEGF, NEGF, NEGF);
        }
        Bm = Bc; Bc = Bp; Bp = Bn;
    }
    if constexpr (DQ) {
        float u0 = __shfl_up(Bc.w, 1);
        float d3 = __shfl_down(Bc.x, 1);
        if (lane == 0)  u0 = NEGF;
        if (lane == 63) d3 = NEGF;
        { const float x = Bc.x; const bool pk = (x >= Bm.x) && (x >= Bp.x) && (x >= u0)   && (x >= Bc.y); c0 += (pk && (x > 0.0f)) ? 1 : 0; }
        { const float x = Bc.y; const bool pk = (x >= Bm.y) && (x >= Bp.y) && (x >= Bc.x) && (x >= Bc.z); c1 += (pk && (x > 0.0f)) ? 1 : 0; }
        { const float x = Bc.z; const bool pk = (x >= Bm.z) && (x >= Bp.z) && (x >= Bc.y) && (x >= Bc.w); c2 += (pk && (x > 0.0f)) ? 1 : 0; }
        { const float x = Bc.w; const bool pk = (x >= Bm.w) && (x >= Bp.w) && (x >= Bc.z) && (x >= d3); c3 += (pk && (x > 0.0f)) ? 1 : 0; }
        lmin = fminf(lmin, fminf(fminf(Bc.x, Bc.y), fminf(Bc.z, Bc.w)));
        lmax = fmaxf(lmax, fmaxf(fmaxf(Bc.x, Bc.y), fmaxf(Bc.z, Bc.w)));
    }
}

__global__ __launch_bounds__(256, 3) void k_march(const float* __restrict__ spec,
                                                  unsigned* __restrict__ mm,
                                                  int* __restrict__ counts2) {
    const int b = blockIdx.y;
    const int lane = threadIdx.x & 63;
    const int wv = threadIdx.x >> 6;
    const int sid = blockIdx.x * 4 + wv;
    const int T0 = sid * TS;

    const float mn = decf(mm[b * 4 + 0]);
    const float mx = decf(mm[b * 4 + 1]);
    const float rinv = 1.0f / (mx - mn);

    const float NEGF = -__builtin_inff();
    const float4 NEG4 = make_float4(NEGF, NEGF, NEGF, NEGF);

    // wave-private single-buffered panel: one 8-col group (256 rows x 2 quads = 8KB)
    __shared__ __align__(16) float sBuf[4][2048];
    float4* myS4 = (float4*)sBuf[wv];

    const int srow = lane >> 1;   // 0..31: row within 32-row slab
    const int sq = lane & 1;      // which 16B quad of the 32B row chunk
    const float* gb = spec + (size_t)b * NF * NT;

    float4 R[8];   // staging registers: one 8-col group (256 rows)
    float4 A[4];   // compute registers: rows 4l..4l+3, one 4-col set

    // group G covers cols T0-8+8G .. +7 ; cols clamped (edge values overridden in regs)
#define GLOAD(G) do {                                                           \
    int tg_ = T0 - 8 + 8 * (G) + 4 * sq;                                        \
    tg_ = (tg_ < 0) ? 0 : ((tg_ > NT - 4) ? (NT - 4) : tg_);                    \
    const float* gp_ = gb + (size_t)srow * NT + tg_;                            \
    _Pragma("unroll")                                                           \
    for (int i = 0; i < 8; ++i)                                                 \
        R[i] = *(const float4*)(gp_ + (size_t)(32 * i) * NT);                   \
} while (0)

    // linear slot 64i+lane holds (row=32i+(lane>>1), q=lane&1); swizzled by ((lane>>3)&7)
#define WRITE() do {                                                            \
    _Pragma("unroll")                                                           \
    for (int i = 0; i < 8; ++i)                                                 \
        myS4[(64 * i + lane) ^ ((lane >> 3) & 7)] = R[i];                       \
} while (0)

    // read rows 4l..4l+3, quad-col QC: slot (8l+2j+QC) ^ (l&7)
#define SREAD(QC) do {                                                          \
    _Pragma("unroll")                                                           \
    for (int j = 0; j < 4; ++j)                                                 \
        A[j] = myS4[(8 * lane + 2 * j + (QC)) ^ (lane & 7)];                    \
} while (0)

    float4 Sa = NEG4, Sb = NEG4, Sc = NEG4;
    float4 V0 = NEG4, V1 = NEG4, V2 = NEG4, V3 = NEG4, V4 = NEG4;
    float4 Bm = NEG4, Bc = NEG4, Bp = NEG4;
    int c0 = 0, c1 = 0, c2 = 0, c3 = 0;
    float lmin = __builtin_inff(), lmax = NEGF;

#define MARGS Sa, Sb, Sc, V0, V1, V2, V3, V4, Bm, Bc, Bp, c0, c1, c2, c3, lmin, lmax, lane, sid, mn, rinv

#define SET_FULL(HB) do { const int hb_ = (HB);                                 \
    march_step<true, true, true, 0>(A[0], A[1], A[2], A[3], MARGS, hb_);        \
    march_step<true, true, true, 1>(A[0], A[1], A[2], A[3], MARGS, hb_);        \
    march_step<true, true, true, 2>(A[0], A[1], A[2], A[3], MARGS, hb_);        \
    march_step<true, true, true, 3>(A[0], A[1], A[2], A[3], MARGS, hb_); } while (0)

    GLOAD(0); WRITE(); GLOAD(1);

    // set 0 (cols T0-4..T0-1, G0 qc1): ring fill + p1 on last two
    SREAD(1);
    if (sid == 0) { A[0] = NEG4; A[1] = NEG4; A[2] = NEG4; A[3] = NEG4; }
    march_step<false, false, false, 0>(A[0], A[1], A[2], A[3], MARGS, 0);
    march_step<false, false, false, 1>(A[0], A[1], A[2], A[3], MARGS, 0);
    march_step<true,  false, false, 2>(A[0], A[1], A[2], A[3], MARGS, 0);
    march_step<true,  false, false, 3>(A[0], A[1], A[2], A[3], MARGS, 0);

    WRITE(); GLOAD(2);
    // set 1 (cols T0..T0+3, G1 qc0): p1; hblur starts on last two (h = T0-1, T0)
    {
        const int hb_ = T0 - 3;
        SREAD(0);
        march_step<true, false, false, 0>(A[0], A[1], A[2], A[3], MARGS, hb_);
        march_step<true, false, false, 1>(A[0], A[1], A[2], A[3], MARGS, hb_);
        march_step<true, true,  false, 2>(A[0], A[1], A[2], A[3], MARGS, hb_);
        march_step<true, true,  false, 3>(A[0], A[1], A[2], A[3], MARGS, hb_);
    }
    // set 2 (G1 qc1): full pipeline starts (hb = T0-7+4s)
    SREAD(1); SET_FULL(T0 + 1);

    WRITE(); GLOAD(3);
    SREAD(0); SET_FULL(T0 + 5);
    SREAD(1); SET_FULL(T0 + 9);

    WRITE(); GLOAD(4);
    SREAD(0); SET_FULL(T0 + 13);
    SREAD(1); SET_FULL(T0 + 17);

    WRITE(); GLOAD(5);
    SREAD(0); SET_FULL(T0 + 21);
    SREAD(1); SET_FULL(T0 + 25);

    WRITE();
    // set 9 (G5 qc0, cols T0+32..35): last set
    SREAD(0);
    if (sid == NSTRIP - 1) { A[0] = NEG4; A[1] = NEG4; A[2] = NEG4; A[3] = NEG4; }
    SET_FULL(T0 + 29);

#undef SET_FULL
#undef GLOAD
#undef WRITE
#undef SREAD
#undef MARGS

    // block-level count combine: all 4 waves cover the same 128-col chunk (= blockIdx.x)
    __syncthreads();
    int* sc = (int*)&sBuf[0][0];
    sc[threadIdx.x * 4 + 0] = c0;
    sc[threadIdx.x * 4 + 1] = c1;
    sc[threadIdx.x * 4 + 2] = c2;
    sc[threadIdx.x * 4 + 3] = c3;
    __syncthreads();
    {
        const int r = threadIdx.x;           // freq row
        const int l = r >> 2, j = r & 3;
        int tot = sc[(0 * 64 + l) * 4 + j] + sc[(1 * 64 + l) * 4 + j]
                + sc[(2 * 64 + l) * 4 + j] + sc[(3 * 64 + l) * 4 + j];
        counts2[(b * NF + r) * 32 + blockIdx.x] = tot;
    }

    for (int off = 32; off; off >>= 1) {
        lmin = fminf(lmin, __shfl_down(lmin, off));
        lmax = fmaxf(lmax, __shfl_down(lmax, off));
    }
    if (lane == 0) {
        atomicMin(&mm[b * 4 + 2], encf(lmin));
        atomicMax(&mm[b * 4 + 3], encf(lmax));
    }
}

// ---------------------------------------------------------------------------
// Tile path (verified): used by k_extract and the never-taken guard in k_prefix.
// ---------------------------------------------------------------------------
__device__ __forceinline__ void blur_tile(const float* __restrict__ sb_base,
                                          int f0, int t0, float mn, float rinv,
                                          float* sR1, float* sR2, int tid,
                                          bool f_lo, bool f_hi, bool t_lo, bool t_hi) {
    const float NEG = -__builtin_inff();
    float* sS = sR1;
    float* sV = sR1;   // overlays sS
    float* sB = sR2;   // overlays sP
    float4* sS4 = (float4*)sR1;
    float4* sP4 = (float4*)sR2;
    float4* sV4 = (float4*)sR1;
    float4* sB4 = (float4*)sR2;

    const bool f_edge = f_lo || f_hi;
    const bool t_edge = t_lo || t_hi;
    const int lane = tid & 63;

    if (!f_edge && !t_edge) {
        const float4* gp = (const float4*)(sb_base + (size_t)(f0 - 4) * NT + (t0 - 4));
        for (int i = tid; i < RS * 34; i += 256) {
            int r = i / 34, c = i - r * 34;
            sS4[r * SW4 + c] = gp[r * (NT / 4) + c];
        }
    } else {
        for (int i = tid; i < RS * 34; i += 256) {
            int r = i / 34, c = i - r * 34;
            int gf = f0 - 4 + r;
            int gc0 = t0 - 4 + 4 * c;
            float4 v = make_float4(NEG, NEG, NEG, NEG);
            if ((unsigned)gf < NF && (unsigned)gc0 < NT)
                v = *(const float4*)(sb_base + (size_t)gf * NT + gc0);
            sS4[r * SW4 + c] = v;
        }
    }
    __syncthreads();

    for (int i = tid; i < RP * 34; i += 256) {
        int r = i / 34, g = i - r * 34;
        const float4 c4 = sS4[(r + 1) * SW4 + g];
        const float4 u4 = sS4[r * SW4 + g];
        const float4 d4 = sS4[(r + 2) * SW4 + g];
        float lm = __shfl_up(c4.w, 1);
        float rp = __shfl_down(c4.x, 1);
        if (lane == 0 && g > 0)   lm = sS[(r + 1) * SW + 4 * g - 1];
        if (lane == 63 && g < 33) rp = sS[(r + 1) * SW + 4 * g + 4];
        float4 o;
        o.x = (c4.x >= lm   && c4.x >= c4.y && c4.x >= u4.x && c4.x >= d4.x) ? (c4.x - mn) * rinv : 0.0f;
        o.y = (c4.y >= c4.x && c4.y >= c4.z && c4.y >= u4.y && c4.y >= d4.y) ? (c4.y - mn) * rinv : 0.0f;
        o.z = (c4.z >= c4.y && c4.z >= c4.w && c4.z >= u4.z && c4.z >= d4.z) ? (c4.z - mn) * rinv : 0.0f;
        o.w = (c4.w >= c4.z && c4.w >= rp   && c4.w >= u4.w && c4.w >= d4.w) ? (c4.w - mn) * rinv : 0.0f;
        if (g == 0) o.x = 0.0f;
        if (g == 33) o.w = 0.0f;
        sP4[r * SW4 + g] = o;
    }
    __syncthreads();

    if (!f_edge) {
        for (int i = tid; i < RV * 34; i += 256) {
            int r = i / 34, g = i - r * 34;
            const float4 p0 = sP4[r * SW4 + g];
            const float4 p1 = sP4[(r + 1) * SW4 + g];
            const float4 p2 = sP4[(r + 2) * SW4 + g];
            const float4 p3 = sP4[(r + 3) * SW4 + g];
            const float4 p4 = sP4[(r + 4) * SW4 + g];
            sV4[r * SW4 + g] = blur5v(p0, p4, p1, p3, p2);
        }
    } else {
        for (int i = tid; i < RV * 34; i += 256) {
            int r = i / 34, g = i - r * 34;
            const int gf = f0 - 1 + r;
            const int r0 = reflectF(gf - 2) - (f0 - 3);
            const int r1 = reflectF(gf - 1) - (f0 - 3);
            const int r2 = gf - (f0 - 3);
            const int r3 = reflectF(gf + 1) - (f0 - 3);
            const int r4 = reflectF(gf + 2) - (f0 - 3);
            const float4 p0 = sP4[r0 * SW4 + g];
            const float4 p1 = sP4[r1 * SW4 + g];
            const float4 p2 = sP4[r2 * SW4 + g];
            const float4 p3 = sP4[r3 * SW4 + g];
            const float4 p4 = sP4[r4 * SW4 + g];
            sV4[r * SW4 + g] = blur5v(p0, p4, p1, p3, p2);
        }
    }
    __syncthreads();

    for (int i = tid; i < RV * 32; i += 256) {
        int r = i >> 5, g = 1 + (i & 31);
        const float4 A = sV4[r * SW4 + g - 1];
        const float4 B = sV4[r * SW4 + g];
        const float4 C = sV4[r * SW4 + g + 1];
        float4 o;
        o.x = blur5(A.z, B.z, A.w, B.y, B.x);
        o.y = blur5(A.w, B.w, B.x, B.z, B.y);
        o.z = blur5(B.x, C.x, B.y, B.w, B.z);
        o.w = blur5(B.y, C.y, B.z, C.x, B.w);
        if (t_lo && g == 1) {
            o.x = blur5(B.z, B.z, B.y, B.y, B.x);
            o.y = blur5(B.y, B.w, B.x, B.z, B.y);
        }
        if (t_hi && g == 32) {
            o.z = blur5(B.x, B.z, B.y, B.w, B.z);
            o.w = blur5(B.y, B.y, B.z, B.z, B.w);
        }
        if ((f_lo && r == 0) || (f_hi && r == 17)) o = make_float4(NEG, NEG, NEG, NEG);
        sB4[r * SW4 + g] = o;
    }
    for (int i = tid; i < RV * 2; i += 256) {
        int r = i >> 1;
        int hi = i & 1;
        int s = hi ? 132 : 3;
        const float* vr = sV + r * SW;
        float v = blur5(vr[s - 2], vr[s + 2], vr[s - 1], vr[s + 1], vr[s]);
        if ((hi ? t_hi : t_lo) || (f_lo && r == 0) || (f_hi && r == 17)) v = NEG;
        sB[r * SW + s] = v;
    }
    __syncthreads();
}

struct Win8 {
    float c[8], l[8], rr[8], u[8], d[8];
};
__device__ __forceinline__ void load_win8(const float4* sB4, int r, int m, Win8& w) {
    const int g = 1 + 2 * m;
    const float4 Cm = sB4[(r + 1) * SW4 + g - 1];
    const float4 C0 = sB4[(r + 1) * SW4 + g];
    const float4 C1 = sB4[(r + 1) * SW4 + g + 1];
    const float4 C2 = sB4[(r + 1) * SW4 + g + 2];
    const float4 U0 = sB4[r * SW4 + g];
    const float4 U1 = sB4[r * SW4 + g + 1];
    const float4 D0 = sB4[(r + 2) * SW4 + g];
    const float4 D1 = sB4[(r + 2) * SW4 + g + 1];
    w.c[0] = C0.x; w.c[1] = C0.y; w.c[2] = C0.z; w.c[3] = C0.w;
    w.c[4] = C1.x; w.c[5] = C1.y; w.c[6] = C1.z; w.c[7] = C1.w;
    w.l[0] = Cm.w; w.l[1] = C0.x; w.l[2] = C0.y; w.l[3] = C0.z;
    w.l[4] = C0.w; w.l[5] = C1.x; w.l[6] = C1.y; w.l[7] = C1.z;
    w.rr[0] = C0.y; w.rr[1] = C0.z; w.rr[2] = C0.w; w.rr[3] = C1.x;
    w.rr[4] = C1.y; w.rr[5] = C1.z; w.rr[6] = C1.w; w.rr[7] = C2.x;
    w.u[0] = U0.x; w.u[1] = U0.y; w.u[2] = U0.z; w.u[3] = U0.w;
    w.u[4] = U1.x; w.u[5] = U1.y; w.u[6] = U1.z; w.u[7] = U1.w;
    w.d[0] = D0.x; w.d[1] = D0.y; w.d[2] = D0.z; w.d[3] = D0.w;
    w.d[4] = D1.x; w.d[5] = D1.y; w.d[6] = D1.z; w.d[7] = D1.w;
}

// k_prefix: per-batch prefix sums; hosts the (never-taken in practice) guard:
// if mn2 != 0 the march counts used threshold 0 and must be redone with x > mn2.
__global__ __launch_bounds__(256) void k_prefix(const float* __restrict__ spec,
                                                unsigned* __restrict__ mm,
                                                int* __restrict__ counts2,
                                                int* __restrict__ prefix2) {
    const int b = blockIdx.x;
    const int tid = threadIdx.x;
    const float mn2 = decf(mm[b * 4 + 2]);
    if (mn2 != 0.0f) {
        __shared__ __align__(16) float sR1[R1_WORDS];
        __shared__ __align__(16) float sR2[R2_WORDS];
        const float4* sB4 = (const float4*)sR2;
        const float mn = decf(mm[b * 4 + 0]);
        const float mx = decf(mm[b * 4 + 1]);
        const float rinv = 1.0f / (mx - mn);
        const float* sb_base = spec + (size_t)b * NF * NT;
        int* pcnt = (int*)sR1;
        for (int ty = 0; ty < NF / TF; ++ty)
        for (int tx = 0; tx < NT / TT; ++tx) {
            blur_tile(sb_base, ty * TF, tx * TT, mn, rinv, sR1, sR2, tid,
                      ty == 0, ty == NF / TF - 1, tx == 0, tx == NT / TT - 1);
            const int r = tid & 15, m = tid >> 4;
            Win8 w;
            load_win8(sB4, r, m, w);
            int cnt = 0;
#pragma unroll
            for (int k = 0; k < 8; k++) {
                float x = w.c[k];
                bool pk = (x >= w.l[k]) && (x >= w.rr[k]) && (x >= w.u[k]) && (x >= w.d[k]);
                cnt += (pk && (x > mn2)) ? 1 : 0;
            }
            (void)m;
            const int lane = tid & 63, wvv = tid >> 6;
            int cs = cnt;
            cs += __shfl_down(cs, 32);
            cs += __shfl_down(cs, 16);
            if (lane < 16) pcnt[wvv * 16 + lane] = cs;
            __syncthreads();
            if (tid < 16)
                counts2[(b * NF + ty * TF + tid) * 32 + tx] =
                    pcnt[tid] + pcnt[16 + tid] + pcnt[32 + tid] + pcnt[48 + tid];
            __syncthreads();
        }
    }
    const int* cb = counts2 + b * NF * 32;
    int* pb = prefix2 + b * NF * 32;
    int local[32];
    int s = 0;
    for (int c = 0; c < 32; c++) {
        local[c] = cb[tid * 32 + c];
        s += local[c];
    }
    __shared__ int tot[256];
    tot[tid] = s;
    __syncthreads();
    for (int off = 1; off < 256; off <<= 1) {
        int v = (tid >= off) ? tot[tid - off] : 0;
        __syncthreads();
        tot[tid] += v;
        __syncthreads();
    }
    int run = tot[tid] - s;
    for (int c = 0; c < 32; c++) {
        pb[tid * 32 + c] = run;
        run += local[c];
    }
}

__global__ __launch_bounds__(256) void k_extract(const float* __restrict__ spec, unsigned* __restrict__ mm,
                                                 const int* __restrict__ prefix2, float* __restrict__ out) {
    const int b = blockIdx.z;
    const int f0 = blockIdx.y * TF;
    const int t0 = blockIdx.x * TT;
    const int c0 = blockIdx.x;
    if (prefix2[(b * NF + f0) * 32 + c0] >= PAD_LEN) return;

    const int tid = threadIdx.x;
    __shared__ __align__(16) float sR1[R1_WORDS];
    __shared__ __align__(16) float sR2[R2_WORDS];
    const float4* sB4 = (const float4*)sR2;

    const float mn = decf(mm[b * 4 + 0]);
    const float mx = decf(mm[b * 4 + 1]);
    const float rinv = 1.0f / (mx - mn);
    const float mn2 = decf(mm[b * 4 + 2]);
    const float mx2 = decf(mm[b * 4 + 3]);
    const float rinv2 = 1.0f / (mx2 - mn2);
    const float* sb_base = spec + (size_t)b * NF * NT;

    const bool f_lo = (blockIdx.y == 0), f_hi = (blockIdx.y == NF / TF - 1);
    const bool t_lo = (blockIdx.x == 0), t_hi = (blockIdx.x == NT / TT - 1);
    blur_tile(sb_base, f0, t0, mn, rinv, sR1, sR2, tid, f_lo, f_hi, t_lo, t_hi);

    const int r = tid & 15, m = tid >> 4;
    const int gf = f0 + r;
    const int base = prefix2[(b * NF + gf) * 32 + c0];
    Win8 w;
    load_win8(sB4, r, m, w);
    bool pos[8];
    int mycnt = 0;
#pragma unroll
    for (int k = 0; k < 8; k++) {
        float x = w.c[k];
        pos[k] = (x >= w.l[k]) && (x >= w.rr[k]) && (x >= w.u[k]) && (x >= w.d[k]) && (x > mn2);
        mycnt += pos[k] ? 1 : 0;
    }
    const int lane = tid & 63, wv = tid >> 6, p = (tid >> 4) & 3;
    int s = mycnt;
    int t1 = __shfl_up(s, 16); if (p >= 1) s += t1;
    int t2 = __shfl_up(s, 32); if (p >= 2) s += t2;
    __shared__ int wtot[4][16];
    if (p == 3) wtot[wv][lane & 15] = s;
    __syncthreads();
    int woff = 0;
    for (int w2 = 0; w2 < wv; ++w2) woff += wtot[w2][r];
    int rank = base + woff + (s - mycnt);
#pragma unroll
    for (int k = 0; k < 8; k++) {
        if (pos[k]) {
            if (rank < PAD_LEN) {
                int gc = t0 + 8 * m + k;
                out[b * 768 + rank]       = (float)gf * (1.0f / 256.0f);
                out[b * 768 + 256 + rank] = (float)gc * (1.0f / 4096.0f);
                out[b * 768 + 512 + rank] = (w.c[k] - mn2) * rinv2;
            }
            rank++;
        }
    }
}

extern "C" void kernel_launch(void* const* d_in, const int* in_sizes, int n_in,
                              void* d_out, int out_size, void* d_ws, size_t ws_size,
                              hipStream_t stream) {
    const float* spec = (const float*)d_in[0];
    float* out = (float*)d_out;
    unsigned* mm = (unsigned*)((char*)d_ws + MM_OFF);
    int* counts2 = (int*)((char*)d_ws + CNT_OFF);
    int* prefix2 = (int*)((char*)d_ws + PFX_OFF);

    k_init<<<96, 256, 0, stream>>>(out, mm);
    k_minmax<<<dim3(64, NB), 256, 0, stream>>>(spec, mm);
    k_march<<<dim3(NSTRIP / 4, NB), 256, 0, stream>>>(spec, mm, counts2);
    k_prefix<<<NB, 256, 0, stream>>>(spec, mm, counts2, prefix2);
    dim3 tgrid(NT / TT, NF / TF, NB);
    k_extract<<<tgrid, 256, 0, stream>>>(spec, mm, prefix2, out);
}

// Round 10
// 349.533 us; speedup vs baseline: 1.1229x; 1.0377x over previous
//
#include <hip/hip_runtime.h>

#define NB 32
#define NF 256
#define NT 4096
#define PAD_LEN 256

#define TF 16
#define TT 128

// k_march strip width (time cols per wave) and strip count.
// TS=32: 128 strips -> 1024 blocks -> 4 waves/SIMD supplied by the grid.
#define TS 32
#define NSTRIP (NT / TS)   // 128

// f32 gaussian weights: exp(-0.5*c^2)/sum, c=-2..2, sigma=1
#define G0 0.054488684f
#define G1 0.24420134f
#define G2 0.40261995f

__device__ __forceinline__ float blur5(float a, float b, float c, float d, float e) {
    return G0 * (a + b) + G1 * (c + d) + G2 * e;
}
__device__ __forceinline__ float4 blur5v(const float4& a, const float4& b, const float4& c,
                                         const float4& d, const float4& e) {
    return make_float4(blur5(a.x, b.x, c.x, d.x, e.x), blur5(a.y, b.y, c.y, d.y, e.y),
                       blur5(a.z, b.z, c.z, d.z, e.z), blur5(a.w, b.w, c.w, d.w, e.w));
}

#define SW 140
#define SW4 35
#define RS 24   // sS rows: global f0-4 .. f0+19
#define RP 22   // sP rows: global f0-3 .. f0+18
#define RV 18   // sV/sB rows: global f0-1 .. f0+16

#define R1_WORDS (RS * SW)
#define R2_WORDS (RP * SW)

__device__ __forceinline__ int reflectF(int i) {
    i = (i < 0) ? -i : i;
    return (i >= NF) ? (2 * NF - 2 - i) : i;
}
__device__ __forceinline__ unsigned encf(float x) {
    unsigned u = __float_as_uint(x);
    return (u & 0x80000000u) ? ~u : (u | 0x80000000u);
}
__device__ __forceinline__ float decf(unsigned e) {
    unsigned u = (e & 0x80000000u) ? (e ^ 0x80000000u) : ~e;
    return __uint_as_float(u);
}

// ws layout: mm[NB][4] @0 ; counts2[NB][NF][32] @1024 ; prefix2 @1024+1MB
#define MM_OFF 0
#define CNT_OFF 1024
#define PFX_OFF (1024 + NB * NF * 32 * 4)

__global__ __launch_bounds__(256) void k_init(float* __restrict__ out, unsigned* __restrict__ mm) {
    int tid = blockIdx.x * 256 + threadIdx.x;
    if (tid < NB * 3 * PAD_LEN) out[tid] = 0.0f;
    if (tid < NB) {
        mm[tid * 4 + 0] = 0xFFFFFFFFu;
        mm[tid * 4 + 1] = 0u;
        mm[tid * 4 + 2] = 0xFFFFFFFFu;
        mm[tid * 4 + 3] = 0u;
    }
}

__global__ __launch_bounds__(256) void k_minmax(const float* __restrict__ spec, unsigned* __restrict__ mm) {
    const int b = blockIdx.y;
    const float4* p = (const float4*)(spec + (size_t)b * NF * NT);
    const int base4 = blockIdx.x * 4096;
    float lmin = __builtin_inff(), lmax = -__builtin_inff();
    for (int i = threadIdx.x; i < 4096; i += 256) {
        float4 v = p[base4 + i];
        lmin = fminf(lmin, fminf(fminf(v.x, v.y), fminf(v.z, v.w)));
        lmax = fmaxf(lmax, fmaxf(fmaxf(v.x, v.y), fmaxf(v.z, v.w)));
    }
    for (int off = 32; off; off >>= 1) {
        lmin = fminf(lmin, __shfl_down(lmin, off));
        lmax = fmaxf(lmax, __shfl_down(lmax, off));
    }
    __shared__ float rmn[4], rmx[4];
    int wave = threadIdx.x >> 6, lane = threadIdx.x & 63;
    if (lane == 0) { rmn[wave] = lmin; rmx[wave] = lmax; }
    __syncthreads();
    if (threadIdx.x == 0) {
        for (int w = 1; w < 4; w++) { lmin = fminf(lmin, rmn[w]); lmax = fmaxf(lmax, rmx[w]); }
        atomicMin(&mm[b * 4 + 0], encf(lmin));
        atomicMax(&mm[b * 4 + 1], encf(lmax));
    }
}

// ---------------------------------------------------------------------------
// k_march: barrier-free rolling-stencil main pass.
// One wave = one 32-col strip x all 256 freq rows (lane l owns rows 4l..4l+3).
// Staging: 8-col groups, R[8] regs (2 lanes/row x 16B, coalesced 32B/row),
// single 8KB/wave LDS panel (32KB/block). GLOAD(G+1) issued before group G's
// compute. Panel swizzle: write banks (l&7)^((l>>3)&1), read (2j+qc)^(l&7).
// R10: launch_bounds (256,3)->(256,2). R9's (,3) forced VGPR to 84 vs the
// ~110 live state -> scratch spills (WRITE_SIZE 107MB, FETCH +150MB, dur 163us).
// Natural allocation ~110-130 VGPR keeps 3-4 waves/SIMD WITHOUT spilling.
// ---------------------------------------------------------------------------

template<int J> __device__ __forceinline__ float getj(const float4& v) {
    if constexpr (J == 0) return v.x;
    else if constexpr (J == 1) return v.y;
    else if constexpr (J == 2) return v.z;
    else return v.w;
}

template<bool DP, bool DH, bool DQ, int J>
__device__ __forceinline__ void march_step(
    const float4& r0, const float4& r1, const float4& r2, const float4& r3,
    float4& Sa, float4& Sb, float4& Sc,
    float4& V0, float4& V1, float4& V2, float4& V3, float4& V4,
    float4& Bm, float4& Bc, float4& Bp,
    int& c0, int& c1, int& c2, int& c3,
    float& lmin, float& lmax,
    const int lane, const int sid, const float mn, const float rinv, const int hb)
{
    const float NEGF = -__builtin_inff();
    float4 X = make_float4(getj<J>(r0), getj<J>(r1), getj<J>(r2), getj<J>(r3));
    Sa = Sb; Sb = Sc; Sc = X;
    if constexpr (DP) {
        float up0 = __shfl_up(Sb.w, 1);
        float dn3 = __shfl_down(Sb.x, 1);
        if (lane == 0)  up0 = NEGF;
        if (lane == 63) dn3 = NEGF;
        float4 P;
        { const float x = Sb.x; const bool pk = (x >= Sa.x) && (x >= Sc.x) && (x >= up0)  && (x >= Sb.y); P.x = pk ? (x - mn) * rinv : 0.0f; }
        { const float x = Sb.y; const bool pk = (x >= Sa.y) && (x >= Sc.y) && (x >= Sb.x) && (x >= Sb.z); P.y = pk ? (x - mn) * rinv : 0.0f; }
        { const float x = Sb.z; const bool pk = (x >= Sa.z) && (x >= Sc.z) && (x >= Sb.y) && (x >= Sb.w); P.z = pk ? (x - mn) * rinv : 0.0f; }
        { const float x = Sb.w; const bool pk = (x >= Sa.w) && (x >= Sc.w) && (x >= Sb.z) && (x >= dn3); P.w = pk ? (x - mn) * rinv : 0.0f; }
        const float pzm = __shfl_up(P.z, 1);     // row 4l-2
        const float pwm = __shfl_up(P.w, 1);     // row 4l-1
        const float pxp = __shfl_down(P.x, 1);   // row 4l+4
        const float pyp = __shfl_down(P.y, 1);   // row 4l+5
        float4 Vn;
        Vn.x = blur5(pzm, P.z, pwm, P.y, P.x);
        Vn.y = blur5(pwm, P.w, P.x, P.z, P.y);
        Vn.z = blur5(P.x, pxp, P.y, P.w, P.z);
        Vn.w = blur5(P.y, pyp, P.z, pxp, P.w);
        if (lane == 0)  { Vn.x = blur5(P.z, P.z, P.y, P.y, P.x);
                          Vn.y = blur5(P.y, P.w, P.x, P.z, P.y); }
        if (lane == 63) { Vn.z = blur5(P.x, P.z, P.y, P.w, P.z);
                          Vn.w = blur5(P.y, P.y, P.z, P.z, P.w); }
        V0 = V1; V1 = V2; V2 = V3; V3 = V4; V4 = Vn;
    }
    if constexpr (DH) {
        const int h = hb + J;
        float4 Bn;
        if ((unsigned)h < (unsigned)NT) {
            Bn = blur5v(V0, V4, V1, V3, V2);
            if (sid == 0) {
                if (h == 0)      Bn = blur5v(V4, V4, V3, V3, V2);
                else if (h == 1) Bn = blur5v(V2, V4, V1, V3, V2);
            }
            if (sid == NSTRIP - 1) {
                if (h == NT - 2)      Bn = blur5v(V0, V2, V1, V3, V2);
                else if (h == NT - 1) Bn = blur5v(V0, V0, V1, V1, V2);
            }
        } else {
            Bn = make_float4(NEGF, NEGF, NEGF, NEGF);
        }
        Bm = Bc; Bc = Bp; Bp = Bn;
    }
    if constexpr (DQ) {
        float u0 = __shfl_up(Bc.w, 1);
        float d3 = __shfl_down(Bc.x, 1);
        if (lane == 0)  u0 = NEGF;
        if (lane == 63) d3 = NEGF;
        { const float x = Bc.x; const bool pk = (x >= Bm.x) && (x >= Bp.x) && (x >= u0)   && (x >= Bc.y); c0 += (pk && (x > 0.0f)) ? 1 : 0; }
        { const float x = Bc.y; const bool pk = (x >= Bm.y) && (x >= Bp.y) && (x >= Bc.x) && (x >= Bc.z); c1 += (pk && (x > 0.0f)) ? 1 : 0; }
        { const float x = Bc.z; const bool pk = (x >= Bm.z) && (x >= Bp.z) && (x >= Bc.y) && (x >= Bc.w); c2 += (pk && (x > 0.0f)) ? 1 : 0; }
        { const float x = Bc.w; const bool pk = (x >= Bm.w) && (x >= Bp.w) && (x >= Bc.z) && (x >= d3); c3 += (pk && (x > 0.0f)) ? 1 : 0; }
        lmin = fminf(lmin, fminf(fminf(Bc.x, Bc.y), fminf(Bc.z, Bc.w)));
        lmax = fmaxf(lmax, fmaxf(fmaxf(Bc.x, Bc.y), fmaxf(Bc.z, Bc.w)));
    }
}

__global__ __launch_bounds__(256, 2) void k_march(const float* __restrict__ spec,
                                                  unsigned* __restrict__ mm,
                                                  int* __restrict__ counts2) {
    const int b = blockIdx.y;
    const int lane = threadIdx.x & 63;
    const int wv = threadIdx.x >> 6;
    const int sid = blockIdx.x * 4 + wv;
    const int T0 = sid * TS;

    const float mn = decf(mm[b * 4 + 0]);
    const float mx = decf(mm[b * 4 + 1]);
    const float rinv = 1.0f / (mx - mn);

    const float NEGF = -__builtin_inff();
    const float4 NEG4 = make_float4(NEGF, NEGF, NEGF, NEGF);

    // wave-private single-buffered panel: one 8-col group (256 rows x 2 quads = 8KB)
    __shared__ __align__(16) float sBuf[4][2048];
    float4* myS4 = (float4*)sBuf[wv];

    const int srow = lane >> 1;   // 0..31: row within 32-row slab
    const int sq = lane & 1;      // which 16B quad of the 32B row chunk
    const float* gb = spec + (size_t)b * NF * NT;

    float4 R[8];   // staging registers: one 8-col group (256 rows)
    float4 A[4];   // compute registers: rows 4l..4l+3, one 4-col set

    // group G covers cols T0-8+8G .. +7 ; cols clamped (edge values overridden in regs)
#define GLOAD(G) do {                                                           \
    int tg_ = T0 - 8 + 8 * (G) + 4 * sq;                                        \
    tg_ = (tg_ < 0) ? 0 : ((tg_ > NT - 4) ? (NT - 4) : tg_);                    \
    const float* gp_ = gb + (size_t)srow * NT + tg_;                            \
    _Pragma("unroll")                                                           \
    for (int i = 0; i < 8; ++i)                                                 \
        R[i] = *(const float4*)(gp_ + (size_t)(32 * i) * NT);                   \
} while (0)

    // linear slot 64i+lane holds (row=32i+(lane>>1), q=lane&1); swizzled by ((lane>>3)&7)
#define WRITE() do {                                                            \
    _Pragma("unroll")                                                           \
    for (int i = 0; i < 8; ++i)                                                 \
        myS4[(64 * i + lane) ^ ((lane >> 3) & 7)] = R[i];                       \
} while (0)

    // read rows 4l..4l+3, quad-col QC: slot (8l+2j+QC) ^ (l&7)
#define SREAD(QC) do {                                                          \
    _Pragma("unroll")                                                           \
    for (int j = 0; j < 4; ++j)                                                 \
        A[j] = myS4[(8 * lane + 2 * j + (QC)) ^ (lane & 7)];                    \
} while (0)

    float4 Sa = NEG4, Sb = NEG4, Sc = NEG4;
    float4 V0 = NEG4, V1 = NEG4, V2 = NEG4, V3 = NEG4, V4 = NEG4;
    float4 Bm = NEG4, Bc = NEG4, Bp = NEG4;
    int c0 = 0, c1 = 0, c2 = 0, c3 = 0;
    float lmin = __builtin_inff(), lmax = NEGF;

#define MARGS Sa, Sb, Sc, V0, V1, V2, V3, V4, Bm, Bc, Bp, c0, c1, c2, c3, lmin, lmax, lane, sid, mn, rinv

#define SET_FULL(HB) do { const int hb_ = (HB);                                 \
    march_step<true, true, true, 0>(A[0], A[1], A[2], A[3], MARGS, hb_);        \
    march_step<true, true, true, 1>(A[0], A[1], A[2], A[3], MARGS, hb_);        \
    march_step<true, true, true, 2>(A[0], A[1], A[2], A[3], MARGS, hb_);        \
    march_step<true, true, true, 3>(A[0], A[1], A[2], A[3], MARGS, hb_); } while (0)

    GLOAD(0); WRITE(); GLOAD(1);

    // set 0 (cols T0-4..T0-1, G0 qc1): ring fill + p1 on last two
    SREAD(1);
    if (sid == 0) { A[0] = NEG4; A[1] = NEG4; A[2] = NEG4; A[3] = NEG4; }
    march_step<false, false, false, 0>(A[0], A[1], A[2], A[3], MARGS, 0);
    march_step<false, false, false, 1>(A[0], A[1], A[2], A[3], MARGS, 0);
    march_step<true,  false, false, 2>(A[0], A[1], A[2], A[3], MARGS, 0);
    march_step<true,  false, false, 3>(A[0], A[1], A[2], A[3], MARGS, 0);

    WRITE(); GLOAD(2);
    // set 1 (cols T0..T0+3, G1 qc0): p1; hblur starts on last two (h = T0-1, T0)
    {
        const int hb_ = T0 - 3;
        SREAD(0);
        march_step<true, false, false, 0>(A[0], A[1], A[2], A[3], MARGS, hb_);
        march_step<true, false, false, 1>(A[0], A[1], A[2], A[3], MARGS, hb_);
        march_step<true, true,  false, 2>(A[0], A[1], A[2], A[3], MARGS, hb_);
        march_step<true, true,  false, 3>(A[0], A[1], A[2], A[3], MARGS, hb_);
    }
    // set 2 (G1 qc1): full pipeline starts (hb = T0-7+4s)
    SREAD(1); SET_FULL(T0 + 1);

    WRITE(); GLOAD(3);
    SREAD(0); SET_FULL(T0 + 5);
    SREAD(1); SET_FULL(T0 + 9);

    WRITE(); GLOAD(4);
    SREAD(0); SET_FULL(T0 + 13);
    SREAD(1); SET_FULL(T0 + 17);

    WRITE(); GLOAD(5);
    SREAD(0); SET_FULL(T0 + 21);
    SREAD(1); SET_FULL(T0 + 25);

    WRITE();
    // set 9 (G5 qc0, cols T0+32..35): last set
    SREAD(0);
    if (sid == NSTRIP - 1) { A[0] = NEG4; A[1] = NEG4; A[2] = NEG4; A[3] = NEG4; }
    SET_FULL(T0 + 29);

#undef SET_FULL
#undef GLOAD
#undef WRITE
#undef SREAD
#undef MARGS

    // block-level count combine: all 4 waves cover the same 128-col chunk (= blockIdx.x)
    __syncthreads();
    int* sc = (int*)&sBuf[0][0];
    sc[threadIdx.x * 4 + 0] = c0;
    sc[threadIdx.x * 4 + 1] = c1;
    sc[threadIdx.x * 4 + 2] = c2;
    sc[threadIdx.x * 4 + 3] = c3;
    __syncthreads();
    {
        const int r = threadIdx.x;           // freq row
        const int l = r >> 2, j = r & 3;
        int tot = sc[(0 * 64 + l) * 4 + j] + sc[(1 * 64 + l) * 4 + j]
                + sc[(2 * 64 + l) * 4 + j] + sc[(3 * 64 + l) * 4 + j];
        counts2[(b * NF + r) * 32 + blockIdx.x] = tot;
    }

    for (int off = 32; off; off >>= 1) {
        lmin = fminf(lmin, __shfl_down(lmin, off));
        lmax = fmaxf(lmax, __shfl_down(lmax, off));
    }
    if (lane == 0) {
        atomicMin(&mm[b * 4 + 2], encf(lmin));
        atomicMax(&mm[b * 4 + 3], encf(lmax));
    }
}

// ---------------------------------------------------------------------------
// Tile path (verified): used by k_extract and the never-taken guard in k_prefix.
// ---------------------------------------------------------------------------
__device__ __forceinline__ void blur_tile(const float* __restrict__ sb_base,
                                          int f0, int t0, float mn, float rinv,
                                          float* sR1, float* sR2, int tid,
                                          bool f_lo, bool f_hi, bool t_lo, bool t_hi) {
    const float NEG = -__builtin_inff();
    float* sS = sR1;
    float* sV = sR1;   // overlays sS
    float* sB = sR2;   // overlays sP
    float4* sS4 = (float4*)sR1;
    float4* sP4 = (float4*)sR2;
    float4* sV4 = (float4*)sR1;
    float4* sB4 = (float4*)sR2;

    const bool f_edge = f_lo || f_hi;
    const bool t_edge = t_lo || t_hi;
    const int lane = tid & 63;

    if (!f_edge && !t_edge) {
        const float4* gp = (const float4*)(sb_base + (size_t)(f0 - 4) * NT + (t0 - 4));
        for (int i = tid; i < RS * 34; i += 256) {
            int r = i / 34, c = i - r * 34;
            sS4[r * SW4 + c] = gp[r * (NT / 4) + c];
        }
    } else {
        for (int i = tid; i < RS * 34; i += 256) {
            int r = i / 34, c = i - r * 34;
            int gf = f0 - 4 + r;
            int gc0 = t0 - 4 + 4 * c;
            float4 v = make_float4(NEG, NEG, NEG, NEG);
            if ((unsigned)gf < NF && (unsigned)gc0 < NT)
                v = *(const float4*)(sb_base + (size_t)gf * NT + gc0);
            sS4[r * SW4 + c] = v;
        }
    }
    __syncthreads();

    for (int i = tid; i < RP * 34; i += 256) {
        int r = i / 34, g = i - r * 34;
        const float4 c4 = sS4[(r + 1) * SW4 + g];
        const float4 u4 = sS4[r * SW4 + g];
        const float4 d4 = sS4[(r + 2) * SW4 + g];
        float lm = __shfl_up(c4.w, 1);
        float rp = __shfl_down(c4.x, 1);
        if (lane == 0 && g > 0)   lm = sS[(r + 1) * SW + 4 * g - 1];
        if (lane == 63 && g < 33) rp = sS[(r + 1) * SW + 4 * g + 4];
        float4 o;
        o.x = (c4.x >= lm   && c4.x >= c4.y && c4.x >= u4.x && c4.x >= d4.x) ? (c4.x - mn) * rinv : 0.0f;
        o.y = (c4.y >= c4.x && c4.y >= c4.z && c4.y >= u4.y && c4.y >= d4.y) ? (c4.y - mn) * rinv : 0.0f;
        o.z = (c4.z >= c4.y && c4.z >= c4.w && c4.z >= u4.z && c4.z >= d4.z) ? (c4.z - mn) * rinv : 0.0f;
        o.w = (c4.w >= c4.z && c4.w >= rp   && c4.w >= u4.w && c4.w >= d4.w) ? (c4.w - mn) * rinv : 0.0f;
        if (g == 0) o.x = 0.0f;
        if (g == 33) o.w = 0.0f;
        sP4[r * SW4 + g] = o;
    }
    __syncthreads();

    if (!f_edge) {
        for (int i = tid; i < RV * 34; i += 256) {
            int r = i / 34, g = i - r * 34;
            const float4 p0 = sP4[r * SW4 + g];
            const float4 p1 = sP4[(r + 1) * SW4 + g];
            const float4 p2 = sP4[(r + 2) * SW4 + g];
            const float4 p3 = sP4[(r + 3) * SW4 + g];
            const float4 p4 = sP4[(r + 4) * SW4 + g];
            sV4[r * SW4 + g] = blur5v(p0, p4, p1, p3, p2);
        }
    } else {
        for (int i = tid; i < RV * 34; i += 256) {
            int r = i / 34, g = i - r * 34;
            const int gf = f0 - 1 + r;
            const int r0 = reflectF(gf - 2) - (f0 - 3);
            const int r1 = reflectF(gf - 1) - (f0 - 3);
            const int r2 = gf - (f0 - 3);
            const int r3 = reflectF(gf + 1) - (f0 - 3);
            const int r4 = reflectF(gf + 2) - (f0 - 3);
            const float4 p0 = sP4[r0 * SW4 + g];
            const float4 p1 = sP4[r1 * SW4 + g];
            const float4 p2 = sP4[r2 * SW4 + g];
            const float4 p3 = sP4[r3 * SW4 + g];
            const float4 p4 = sP4[r4 * SW4 + g];
            sV4[r * SW4 + g] = blur5v(p0, p4, p1, p3, p2);
        }
    }
    __syncthreads();

    for (int i = tid; i < RV * 32; i += 256) {
        int r = i >> 5, g = 1 + (i & 31);
        const float4 A = sV4[r * SW4 + g - 1];
        const float4 B = sV4[r * SW4 + g];
        const float4 C = sV4[r * SW4 + g + 1];
        float4 o;
        o.x = blur5(A.z, B.z, A.w, B.y, B.x);
        o.y = blur5(A.w, B.w, B.x, B.z, B.y);
        o.z = blur5(B.x, C.x, B.y, B.w, B.z);
        o.w = blur5(B.y, C.y, B.z, C.x, B.w);
        if (t_lo && g == 1) {
            o.x = blur5(B.z, B.z, B.y, B.y, B.x);
            o.y = blur5(B.y, B.w, B.x, B.z, B.y);
        }
        if (t_hi && g == 32) {
            o.z = blur5(B.x, B.z, B.y, B.w, B.z);
            o.w = blur5(B.y, B.y, B.z, B.z, B.w);
        }
        if ((f_lo && r == 0) || (f_hi && r == 17)) o = make_float4(NEG, NEG, NEG, NEG);
        sB4[r * SW4 + g] = o;
    }
    for (int i = tid; i < RV * 2; i += 256) {
        int r = i >> 1;
        int hi = i & 1;
        int s = hi ? 132 : 3;
        const float* vr = sV + r * SW;
        float v = blur5(vr[s - 2], vr[s + 2], vr[s - 1], vr[s + 1], vr[s]);
        if ((hi ? t_hi : t_lo) || (f_lo && r == 0) || (f_hi && r == 17)) v = NEG;
        sB[r * SW + s] = v;
    }
    __syncthreads();
}

struct Win8 {
    float c[8], l[8], rr[8], u[8], d[8];
};
__device__ __forceinline__ void load_win8(const float4* sB4, int r, int m, Win8& w) {
    const int g = 1 + 2 * m;
    const float4 Cm = sB4[(r + 1) * SW4 + g - 1];
    const float4 C0 = sB4[(r + 1) * SW4 + g];
    const float4 C1 = sB4[(r + 1) * SW4 + g + 1];
    const float4 C2 = sB4[(r + 1) * SW4 + g + 2];
    const float4 U0 = sB4[r * SW4 + g];
    const float4 U1 = sB4[r * SW4 + g + 1];
    const float4 D0 = sB4[(r + 2) * SW4 + g];
    const float4 D1 = sB4[(r + 2) * SW4 + g + 1];
    w.c[0] = C0.x; w.c[1] = C0.y; w.c[2] = C0.z; w.c[3] = C0.w;
    w.c[4] = C1.x; w.c[5] = C1.y; w.c[6] = C1.z; w.c[7] = C1.w;
    w.l[0] = Cm.w; w.l[1] = C0.x; w.l[2] = C0.y; w.l[3] = C0.z;
    w.l[4] = C0.w; w.l[5] = C1.x; w.l[6] = C1.y; w.l[7] = C1.z;
    w.rr[0] = C0.y; w.rr[1] = C0.z; w.rr[2] = C0.w; w.rr[3] = C1.x;
    w.rr[4] = C1.y; w.rr[5] = C1.z; w.rr[6] = C1.w; w.rr[7] = C2.x;
    w.u[0] = U0.x; w.u[1] = U0.y; w.u[2] = U0.z; w.u[3] = U0.w;
    w.u[4] = U1.x; w.u[5] = U1.y; w.u[6] = U1.z; w.u[7] = U1.w;
    w.d[0] = D0.x; w.d[1] = D0.y; w.d[2] = D0.z; w.d[3] = D0.w;
    w.d[4] = D1.x; w.d[5] = D1.y; w.d[6] = D1.z; w.d[7] = D1.w;
}

// k_prefix: per-batch prefix sums; hosts the (never-taken in practice) guard:
// if mn2 != 0 the march counts used threshold 0 and must be redone with x > mn2.
__global__ __launch_bounds__(256) void k_prefix(const float* __restrict__ spec,
                                                unsigned* __restrict__ mm,
                                                int* __restrict__ counts2,
                                                int* __restrict__ prefix2) {
    const int b = blockIdx.x;
    const int tid = threadIdx.x;
    const float mn2 = decf(mm[b * 4 + 2]);
    if (mn2 != 0.0f) {
        __shared__ __align__(16) float sR1[R1_WORDS];
        __shared__ __align__(16) float sR2[R2_WORDS];
        const float4* sB4 = (const float4*)sR2;
        const float mn = decf(mm[b * 4 + 0]);
        const float mx = decf(mm[b * 4 + 1]);
        const float rinv = 1.0f / (mx - mn);
        const float* sb_base = spec + (size_t)b * NF * NT;
        int* pcnt = (int*)sR1;
        for (int ty = 0; ty < NF / TF; ++ty)
        for (int tx = 0; tx < NT / TT; ++tx) {
            blur_tile(sb_base, ty * TF, tx * TT, mn, rinv, sR1, sR2, tid,
                      ty == 0, ty == NF / TF - 1, tx == 0, tx == NT / TT - 1);
            const int r = tid & 15, m = tid >> 4;
            Win8 w;
            load_win8(sB4, r, m, w);
            int cnt = 0;
#pragma unroll
            for (int k = 0; k < 8; k++) {
                float x = w.c[k];
                bool pk = (x >= w.l[k]) && (x >= w.rr[k]) && (x >= w.u[k]) && (x >= w.d[k]);
                cnt += (pk && (x > mn2)) ? 1 : 0;
            }
            (void)m;
            const int lane = tid & 63, wvv = tid >> 6;
            int cs = cnt;
            cs += __shfl_down(cs, 32);
            cs += __shfl_down(cs, 16);
            if (lane < 16) pcnt[wvv * 16 + lane] = cs;
            __syncthreads();
            if (tid < 16)
                counts2[(b * NF + ty * TF + tid) * 32 + tx] =
                    pcnt[tid] + pcnt[16 + tid] + pcnt[32 + tid] + pcnt[48 + tid];
            __syncthreads();
        }
    }
    const int* cb = counts2 + b * NF * 32;
    int* pb = prefix2 + b * NF * 32;
    int local[32];
    int s = 0;
    for (int c = 0; c < 32; c++) {
        local[c] = cb[tid * 32 + c];
        s += local[c];
    }
    __shared__ int tot[256];
    tot[tid] = s;
    __syncthreads();
    for (int off = 1; off < 256; off <<= 1) {
        int v = (tid >= off) ? tot[tid - off] : 0;
        __syncthreads();
        tot[tid] += v;
        __syncthreads();
    }
    int run = tot[tid] - s;
    for (int c = 0; c < 32; c++) {
        pb[tid * 32 + c] = run;
        run += local[c];
    }
}

__global__ __launch_bounds__(256) void k_extract(const float* __restrict__ spec, unsigned* __restrict__ mm,
                                                 const int* __restrict__ prefix2, float* __restrict__ out) {
    const int b = blockIdx.z;
    const int f0 = blockIdx.y * TF;
    const int t0 = blockIdx.x * TT;
    const int c0 = blockIdx.x;
    if (prefix2[(b * NF + f0) * 32 + c0] >= PAD_LEN) return;

    const int tid = threadIdx.x;
    __shared__ __align__(16) float sR1[R1_WORDS];
    __shared__ __align__(16) float sR2[R2_WORDS];
    const float4* sB4 = (const float4*)sR2;

    const float mn = decf(mm[b * 4 + 0]);
    const float mx = decf(mm[b * 4 + 1]);
    const float rinv = 1.0f / (mx - mn);
    const float mn2 = decf(mm[b * 4 + 2]);
    const float mx2 = decf(mm[b * 4 + 3]);
    const float rinv2 = 1.0f / (mx2 - mn2);
    const float* sb_base = spec + (size_t)b * NF * NT;

    const bool f_lo = (blockIdx.y == 0), f_hi = (blockIdx.y == NF / TF - 1);
    const bool t_lo = (blockIdx.x == 0), t_hi = (blockIdx.x == NT / TT - 1);
    blur_tile(sb_base, f0, t0, mn, rinv, sR1, sR2, tid, f_lo, f_hi, t_lo, t_hi);

    const int r = tid & 15, m = tid >> 4;
    const int gf = f0 + r;
    const int base = prefix2[(b * NF + gf) * 32 + c0];
    Win8 w;
    load_win8(sB4, r, m, w);
    bool pos[8];
    int mycnt = 0;
#pragma unroll
    for (int k = 0; k < 8; k++) {
        float x = w.c[k];
        pos[k] = (x >= w.l[k]) && (x >= w.rr[k]) && (x >= w.u[k]) && (x >= w.d[k]) && (x > mn2);
        mycnt += pos[k] ? 1 : 0;
    }
    const int lane = tid & 63, wv = tid >> 6, p = (tid >> 4) & 3;
    int s = mycnt;
    int t1 = __shfl_up(s, 16); if (p >= 1) s += t1;
    int t2 = __shfl_up(s, 32); if (p >= 2) s += t2;
    __shared__ int wtot[4][16];
    if (p == 3) wtot[wv][lane & 15] = s;
    __syncthreads();
    int woff = 0;
    for (int w2 = 0; w2 < wv; ++w2) woff += wtot[w2][r];
    int rank = base + woff + (s - mycnt);
#pragma unroll
    for (int k = 0; k < 8; k++) {
        if (pos[k]) {
            if (rank < PAD_LEN) {
                int gc = t0 + 8 * m + k;
                out[b * 768 + rank]       = (float)gf * (1.0f / 256.0f);
                out[b * 768 + 256 + rank] = (float)gc * (1.0f / 4096.0f);
                out[b * 768 + 512 + rank] = (w.c[k] - mn2) * rinv2;
            }
            rank++;
        }
    }
}

extern "C" void kernel_launch(void* const* d_in, const int* in_sizes, int n_in,
                              void* d_out, int out_size, void* d_ws, size_t ws_size,
                              hipStream_t stream) {
    const float* spec = (const float*)d_in[0];
    float* out = (float*)d_out;
    unsigned* mm = (unsigned*)((char*)d_ws + MM_OFF);
    int* counts2 = (int*)((char*)d_ws + CNT_OFF);
    int* prefix2 = (int*)((char*)d_ws + PFX_OFF);

    k_init<<<96, 256, 0, stream>>>(out, mm);
    k_minmax<<<dim3(64, NB), 256, 0, stream>>>(spec, mm);
    k_march<<<dim3(NSTRIP / 4, NB), 256, 0, stream>>>(spec, mm, counts2);
    k_prefix<<<NB, 256, 0, stream>>>(spec, mm, counts2, prefix2);
    dim3 tgrid(NT / TT, NF / TF, NB);
    k_extract<<<tgrid, 256, 0, stream>>>(spec, mm, prefix2, out);
}

// Round 11
// 328.430 us; speedup vs baseline: 1.1951x; 1.0643x over previous
//
#include <hip/hip_runtime.h>

#define NB 32
#define NF 256
#define NT 4096
#define PAD_LEN 256

#define TF 16
#define TT 128

// k_march strip width (time cols per wave) and strip count.
// TS=32: 128 strips -> 1024 blocks -> 4 waves/SIMD supplied by the grid.
#define TS 32
#define NSTRIP (NT / TS)   // 128

// f32 gaussian weights: exp(-0.5*c^2)/sum, c=-2..2, sigma=1
#define G0 0.054488684f
#define G1 0.24420134f
#define G2 0.40261995f

__device__ __forceinline__ float blur5(float a, float b, float c, float d, float e) {
    return G0 * (a + b) + G1 * (c + d) + G2 * e;
}
__device__ __forceinline__ float4 blur5v(const float4& a, const float4& b, const float4& c,
                                         const float4& d, const float4& e) {
    return make_float4(blur5(a.x, b.x, c.x, d.x, e.x), blur5(a.y, b.y, c.y, d.y, e.y),
                       blur5(a.z, b.z, c.z, d.z, e.z), blur5(a.w, b.w, c.w, d.w, e.w));
}

#define SW 140
#define SW4 35
#define RS 24   // sS rows: global f0-4 .. f0+19
#define RP 22   // sP rows: global f0-3 .. f0+18
#define RV 18   // sV/sB rows: global f0-1 .. f0+16

#define R1_WORDS (RS * SW)
#define R2_WORDS (RP * SW)

__device__ __forceinline__ int reflectF(int i) {
    i = (i < 0) ? -i : i;
    return (i >= NF) ? (2 * NF - 2 - i) : i;
}
__device__ __forceinline__ unsigned encf(float x) {
    unsigned u = __float_as_uint(x);
    return (u & 0x80000000u) ? ~u : (u | 0x80000000u);
}
__device__ __forceinline__ float decf(unsigned e) {
    unsigned u = (e & 0x80000000u) ? (e ^ 0x80000000u) : ~e;
    return __uint_as_float(u);
}

// ws layout: mm[NB][4] @0 ; counts2[NB][NF][32] @1024 ; prefix2 @1024+1MB
#define MM_OFF 0
#define CNT_OFF 1024
#define PFX_OFF (1024 + NB * NF * 32 * 4)

__global__ __launch_bounds__(256) void k_init(float* __restrict__ out, unsigned* __restrict__ mm) {
    int tid = blockIdx.x * 256 + threadIdx.x;
    if (tid < NB * 3 * PAD_LEN) out[tid] = 0.0f;
    if (tid < NB) {
        mm[tid * 4 + 0] = 0xFFFFFFFFu;
        mm[tid * 4 + 1] = 0u;
        mm[tid * 4 + 2] = 0xFFFFFFFFu;
        mm[tid * 4 + 3] = 0u;
    }
}

__global__ __launch_bounds__(256) void k_minmax(const float* __restrict__ spec, unsigned* __restrict__ mm) {
    const int b = blockIdx.y;
    const float4* p = (const float4*)(spec + (size_t)b * NF * NT);
    const int base4 = blockIdx.x * 4096;
    float lmin = __builtin_inff(), lmax = -__builtin_inff();
    for (int i = threadIdx.x; i < 4096; i += 256) {
        float4 v = p[base4 + i];
        lmin = fminf(lmin, fminf(fminf(v.x, v.y), fminf(v.z, v.w)));
        lmax = fmaxf(lmax, fmaxf(fmaxf(v.x, v.y), fmaxf(v.z, v.w)));
    }
    for (int off = 32; off; off >>= 1) {
        lmin = fminf(lmin, __shfl_down(lmin, off));
        lmax = fmaxf(lmax, __shfl_down(lmax, off));
    }
    __shared__ float rmn[4], rmx[4];
    int wave = threadIdx.x >> 6, lane = threadIdx.x & 63;
    if (lane == 0) { rmn[wave] = lmin; rmx[wave] = lmax; }
    __syncthreads();
    if (threadIdx.x == 0) {
        for (int w = 1; w < 4; w++) { lmin = fminf(lmin, rmn[w]); lmax = fmaxf(lmax, rmx[w]); }
        atomicMin(&mm[b * 4 + 0], encf(lmin));
        atomicMax(&mm[b * 4 + 1], encf(lmax));
    }
}

// ---------------------------------------------------------------------------
// k_march: barrier-free rolling-stencil main pass.
// One wave = one 32-col strip x all 256 freq rows (lane l owns rows 4l..4l+3).
// R11: PAIR-ADJACENT staging. R10's 8-col groups issued the two 32B halves of
// each 64B line ~1100cyc apart -> each 32B miss fetched the full 64B line ->
// FETCH 2x ideal (385MB). Now line pairs (G1,G2),(G3,G4) load back-to-back into
// Ra/Rb so both halves are in the MSHR window together -> one fetch per line.
// Two 8KB LDS panels (A,B) per wave (64KB/block, 2 blocks/CU = 8 waves/CU).
// Column/set sequence identical to R10 (bit-identical output).
// ---------------------------------------------------------------------------

template<int J> __device__ __forceinline__ float getj(const float4& v) {
    if constexpr (J == 0) return v.x;
    else if constexpr (J == 1) return v.y;
    else if constexpr (J == 2) return v.z;
    else return v.w;
}

template<bool DP, bool DH, bool DQ, int J>
__device__ __forceinline__ void march_step(
    const float4& r0, const float4& r1, const float4& r2, const float4& r3,
    float4& Sa, float4& Sb, float4& Sc,
    float4& V0, float4& V1, float4& V2, float4& V3, float4& V4,
    float4& Bm, float4& Bc, float4& Bp,
    int& c0, int& c1, int& c2, int& c3,
    float& lmin, float& lmax,
    const int lane, const int sid, const float mn, const float rinv, const int hb)
{
    const float NEGF = -__builtin_inff();
    float4 X = make_float4(getj<J>(r0), getj<J>(r1), getj<J>(r2), getj<J>(r3));
    Sa = Sb; Sb = Sc; Sc = X;
    if constexpr (DP) {
        float up0 = __shfl_up(Sb.w, 1);
        float dn3 = __shfl_down(Sb.x, 1);
        if (lane == 0)  up0 = NEGF;
        if (lane == 63) dn3 = NEGF;
        float4 P;
        { const float x = Sb.x; const bool pk = (x >= Sa.x) && (x >= Sc.x) && (x >= up0)  && (x >= Sb.y); P.x = pk ? (x - mn) * rinv : 0.0f; }
        { const float x = Sb.y; const bool pk = (x >= Sa.y) && (x >= Sc.y) && (x >= Sb.x) && (x >= Sb.z); P.y = pk ? (x - mn) * rinv : 0.0f; }
        { const float x = Sb.z; const bool pk = (x >= Sa.z) && (x >= Sc.z) && (x >= Sb.y) && (x >= Sb.w); P.z = pk ? (x - mn) * rinv : 0.0f; }
        { const float x = Sb.w; const bool pk = (x >= Sa.w) && (x >= Sc.w) && (x >= Sb.z) && (x >= dn3); P.w = pk ? (x - mn) * rinv : 0.0f; }
        const float pzm = __shfl_up(P.z, 1);     // row 4l-2
        const float pwm = __shfl_up(P.w, 1);     // row 4l-1
        const float pxp = __shfl_down(P.x, 1);   // row 4l+4
        const float pyp = __shfl_down(P.y, 1);   // row 4l+5
        float4 Vn;
        Vn.x = blur5(pzm, P.z, pwm, P.y, P.x);
        Vn.y = blur5(pwm, P.w, P.x, P.z, P.y);
        Vn.z = blur5(P.x, pxp, P.y, P.w, P.z);
        Vn.w = blur5(P.y, pyp, P.z, pxp, P.w);
        if (lane == 0)  { Vn.x = blur5(P.z, P.z, P.y, P.y, P.x);
                          Vn.y = blur5(P.y, P.w, P.x, P.z, P.y); }
        if (lane == 63) { Vn.z = blur5(P.x, P.z, P.y, P.w, P.z);
                          Vn.w = blur5(P.y, P.y, P.z, P.z, P.w); }
        V0 = V1; V1 = V2; V2 = V3; V3 = V4; V4 = Vn;
    }
    if constexpr (DH) {
        const int h = hb + J;
        float4 Bn;
        if ((unsigned)h < (unsigned)NT) {
            Bn = blur5v(V0, V4, V1, V3, V2);
            if (sid == 0) {
                if (h == 0)      Bn = blur5v(V4, V4, V3, V3, V2);
                else if (h == 1) Bn = blur5v(V2, V4, V1, V3, V2);
            }
            if (sid == NSTRIP - 1) {
                if (h == NT - 2)      Bn = blur5v(V0, V2, V1, V3, V2);
                else if (h == NT - 1) Bn = blur5v(V0, V0, V1, V1, V2);
            }
        } else {
            Bn = make_float4(NEGF, NEGF, NEGF, NEGF);
        }
        Bm = Bc; Bc = Bp; Bp = Bn;
    }
    if constexpr (DQ) {
        float u0 = __shfl_up(Bc.w, 1);
        float d3 = __shfl_down(Bc.x, 1);
        if (lane == 0)  u0 = NEGF;
        if (lane == 63) d3 = NEGF;
        { const float x = Bc.x; const bool pk = (x >= Bm.x) && (x >= Bp.x) && (x >= u0)   && (x >= Bc.y); c0 += (pk && (x > 0.0f)) ? 1 : 0; }
        { const float x = Bc.y; const bool pk = (x >= Bm.y) && (x >= Bp.y) && (x >= Bc.x) && (x >= Bc.z); c1 += (pk && (x > 0.0f)) ? 1 : 0; }
        { const float x = Bc.z; const bool pk = (x >= Bm.z) && (x >= Bp.z) && (x >= Bc.y) && (x >= Bc.w); c2 += (pk && (x > 0.0f)) ? 1 : 0; }
        { const float x = Bc.w; const bool pk = (x >= Bm.w) && (x >= Bp.w) && (x >= Bc.z) && (x >= d3); c3 += (pk && (x > 0.0f)) ? 1 : 0; }
        lmin = fminf(lmin, fminf(fminf(Bc.x, Bc.y), fminf(Bc.z, Bc.w)));
        lmax = fmaxf(lmax, fmaxf(fmaxf(Bc.x, Bc.y), fmaxf(Bc.z, Bc.w)));
    }
}

__global__ __launch_bounds__(256, 2) void k_march(const float* __restrict__ spec,
                                                  unsigned* __restrict__ mm,
                                                  int* __restrict__ counts2) {
    const int b = blockIdx.y;
    const int lane = threadIdx.x & 63;
    const int wv = threadIdx.x >> 6;
    const int sid = blockIdx.x * 4 + wv;
    const int T0 = sid * TS;

    const float mn = decf(mm[b * 4 + 0]);
    const float mx = decf(mm[b * 4 + 1]);
    const float rinv = 1.0f / (mx - mn);

    const float NEGF = -__builtin_inff();
    const float4 NEG4 = make_float4(NEGF, NEGF, NEGF, NEGF);

    // two wave-private panels, 8KB each (one 8-col group = 256 rows x 2 quads)
    __shared__ __align__(16) float sBuf[4][2][2048];
    float4* pA = (float4*)sBuf[wv][0];
    float4* pB = (float4*)sBuf[wv][1];

    const int srow = lane >> 1;   // 0..31: row within 32-row slab
    const int sq = lane & 1;      // which 16B quad of the 32B row chunk
    const float* gb = spec + (size_t)b * NF * NT;

    float4 Ra[8], Rb[8];   // staging registers: two 8-col groups (256 rows each)
    float4 A[4];           // compute registers: rows 4l..4l+3, one 4-col set

    // group G covers cols T0-8+8G .. +7 ; cols clamped (edge values overridden in regs)
#define GLOAD(RR, G) do {                                                       \
    int tg_ = T0 - 8 + 8 * (G) + 4 * sq;                                        \
    tg_ = (tg_ < 0) ? 0 : ((tg_ > NT - 4) ? (NT - 4) : tg_);                    \
    const float* gp_ = gb + (size_t)srow * NT + tg_;                            \
    _Pragma("unroll")                                                           \
    for (int i = 0; i < 8; ++i)                                                 \
        RR[i] = *(const float4*)(gp_ + (size_t)(32 * i) * NT);                  \
} while (0)

    // linear slot 64i+lane holds (row=32i+(lane>>1), q=lane&1); swizzled by ((lane>>3)&7)
#define WRITEP(P, RR) do {                                                      \
    _Pragma("unroll")                                                           \
    for (int i = 0; i < 8; ++i)                                                 \
        (P)[(64 * i + lane) ^ ((lane >> 3) & 7)] = RR[i];                       \
} while (0)

    // read rows 4l..4l+3, quad-col QC: slot (8l+2j+QC) ^ (l&7)
#define SREADP(P, QC) do {                                                      \
    _Pragma("unroll")                                                           \
    for (int j = 0; j < 4; ++j)                                                 \
        A[j] = (P)[(8 * lane + 2 * j + (QC)) ^ (lane & 7)];                     \
} while (0)

    float4 Sa = NEG4, Sb = NEG4, Sc = NEG4;
    float4 V0 = NEG4, V1 = NEG4, V2 = NEG4, V3 = NEG4, V4 = NEG4;
    float4 Bm = NEG4, Bc = NEG4, Bp = NEG4;
    int c0 = 0, c1 = 0, c2 = 0, c3 = 0;
    float lmin = __builtin_inff(), lmax = NEGF;

#define MARGS Sa, Sb, Sc, V0, V1, V2, V3, V4, Bm, Bc, Bp, c0, c1, c2, c3, lmin, lmax, lane, sid, mn, rinv

#define SET_FULL(HB) do { const int hb_ = (HB);                                 \
    march_step<true, true, true, 0>(A[0], A[1], A[2], A[3], MARGS, hb_);        \
    march_step<true, true, true, 1>(A[0], A[1], A[2], A[3], MARGS, hb_);        \
    march_step<true, true, true, 2>(A[0], A[1], A[2], A[3], MARGS, hb_);        \
    march_step<true, true, true, 3>(A[0], A[1], A[2], A[3], MARGS, hb_); } while (0)

    GLOAD(Ra, 0); WRITEP(pA, Ra);            // A = G0
    GLOAD(Ra, 1); GLOAD(Rb, 2);              // line pair (G1,G2) back-to-back

    // set 0 (cols T0-4..T0-1, G0 qc1): ring fill + p1 on last two
    SREADP(pA, 1);
    if (sid == 0) { A[0] = NEG4; A[1] = NEG4; A[2] = NEG4; A[3] = NEG4; }
    march_step<false, false, false, 0>(A[0], A[1], A[2], A[3], MARGS, 0);
    march_step<false, false, false, 1>(A[0], A[1], A[2], A[3], MARGS, 0);
    march_step<true,  false, false, 2>(A[0], A[1], A[2], A[3], MARGS, 0);
    march_step<true,  false, false, 3>(A[0], A[1], A[2], A[3], MARGS, 0);

    WRITEP(pB, Ra);                          // B = G1
    WRITEP(pA, Rb);                          // A = G2 (A's set 0 already consumed)
    GLOAD(Ra, 3); GLOAD(Rb, 4);              // line pair (G3,G4) back-to-back

    // set 1 (cols T0..T0+3, G1 qc0): p1; hblur starts on last two (h = T0-1, T0)
    {
        const int hb_ = T0 - 3;
        SREADP(pB, 0);
        march_step<true, false, false, 0>(A[0], A[1], A[2], A[3], MARGS, hb_);
        march_step<true, false, false, 1>(A[0], A[1], A[2], A[3], MARGS, hb_);
        march_step<true, true,  false, 2>(A[0], A[1], A[2], A[3], MARGS, hb_);
        march_step<true, true,  false, 3>(A[0], A[1], A[2], A[3], MARGS, hb_);
    }
    // sets 2..4: full pipeline (hb = T0-7+4s)
    SREADP(pB, 1); SET_FULL(T0 + 1);
    SREADP(pA, 0); SET_FULL(T0 + 5);
    SREADP(pA, 1); SET_FULL(T0 + 9);

    WRITEP(pB, Ra);                          // B = G3
    WRITEP(pA, Rb);                          // A = G4
    GLOAD(Ra, 5);                            // G5 (boundary half-line, solo)

    SREADP(pB, 0); SET_FULL(T0 + 13);
    SREADP(pB, 1); SET_FULL(T0 + 17);
    SREADP(pA, 0); SET_FULL(T0 + 21);
    SREADP(pA, 1); SET_FULL(T0 + 25);

    WRITEP(pB, Ra);                          // B = G5
    // set 9 (G5 qc0, cols T0+32..35): last set
    SREADP(pB, 0);
    if (sid == NSTRIP - 1) { A[0] = NEG4; A[1] = NEG4; A[2] = NEG4; A[3] = NEG4; }
    SET_FULL(T0 + 29);

#undef SET_FULL
#undef GLOAD
#undef WRITEP
#undef SREADP
#undef MARGS

    // block-level count combine: all 4 waves cover the same 128-col chunk (= blockIdx.x)
    __syncthreads();
    int* sc = (int*)&sBuf[0][0][0];
    sc[threadIdx.x * 4 + 0] = c0;
    sc[threadIdx.x * 4 + 1] = c1;
    sc[threadIdx.x * 4 + 2] = c2;
    sc[threadIdx.x * 4 + 3] = c3;
    __syncthreads();
    {
        const int r = threadIdx.x;           // freq row
        const int l = r >> 2, j = r & 3;
        int tot = sc[(0 * 64 + l) * 4 + j] + sc[(1 * 64 + l) * 4 + j]
                + sc[(2 * 64 + l) * 4 + j] + sc[(3 * 64 + l) * 4 + j];
        counts2[(b * NF + r) * 32 + blockIdx.x] = tot;
    }

    for (int off = 32; off; off >>= 1) {
        lmin = fminf(lmin, __shfl_down(lmin, off));
        lmax = fmaxf(lmax, __shfl_down(lmax, off));
    }
    if (lane == 0) {
        atomicMin(&mm[b * 4 + 2], encf(lmin));
        atomicMax(&mm[b * 4 + 3], encf(lmax));
    }
}

// ---------------------------------------------------------------------------
// Tile path (verified): used by k_extract and the never-taken guard in k_prefix.
// ---------------------------------------------------------------------------
__device__ __forceinline__ void blur_tile(const float* __restrict__ sb_base,
                                          int f0, int t0, float mn, float rinv,
                                          float* sR1, float* sR2, int tid,
                                          bool f_lo, bool f_hi, bool t_lo, bool t_hi) {
    const float NEG = -__builtin_inff();
    float* sS = sR1;
    float* sV = sR1;   // overlays sS
    float* sB = sR2;   // overlays sP
    float4* sS4 = (float4*)sR1;
    float4* sP4 = (float4*)sR2;
    float4* sV4 = (float4*)sR1;
    float4* sB4 = (float4*)sR2;

    const bool f_edge = f_lo || f_hi;
    const bool t_edge = t_lo || t_hi;
    const int lane = tid & 63;

    if (!f_edge && !t_edge) {
        const float4* gp = (const float4*)(sb_base + (size_t)(f0 - 4) * NT + (t0 - 4));
        for (int i = tid; i < RS * 34; i += 256) {
            int r = i / 34, c = i - r * 34;
            sS4[r * SW4 + c] = gp[r * (NT / 4) + c];
        }
    } else {
        for (int i = tid; i < RS * 34; i += 256) {
            int r = i / 34, c = i - r * 34;
            int gf = f0 - 4 + r;
            int gc0 = t0 - 4 + 4 * c;
            float4 v = make_float4(NEG, NEG, NEG, NEG);
            if ((unsigned)gf < NF && (unsigned)gc0 < NT)
                v = *(const float4*)(sb_base + (size_t)gf * NT + gc0);
            sS4[r * SW4 + c] = v;
        }
    }
    __syncthreads();

    for (int i = tid; i < RP * 34; i += 256) {
        int r = i / 34, g = i - r * 34;
        const float4 c4 = sS4[(r + 1) * SW4 + g];
        const float4 u4 = sS4[r * SW4 + g];
        const float4 d4 = sS4[(r + 2) * SW4 + g];
        float lm = __shfl_up(c4.w, 1);
        float rp = __shfl_down(c4.x, 1);
        if (lane == 0 && g > 0)   lm = sS[(r + 1) * SW + 4 * g - 1];
        if (lane == 63 && g < 33) rp = sS[(r + 1) * SW + 4 * g + 4];
        float4 o;
        o.x = (c4.x >= lm   && c4.x >= c4.y && c4.x >= u4.x && c4.x >= d4.x) ? (c4.x - mn) * rinv : 0.0f;
        o.y = (c4.y >= c4.x && c4.y >= c4.z && c4.y >= u4.y && c4.y >= d4.y) ? (c4.y - mn) * rinv : 0.0f;
        o.z = (c4.z >= c4.y && c4.z >= c4.w && c4.z >= u4.z && c4.z >= d4.z) ? (c4.z - mn) * rinv : 0.0f;
        o.w = (c4.w >= c4.z && c4.w >= rp   && c4.w >= u4.w && c4.w >= d4.w) ? (c4.w - mn) * rinv : 0.0f;
        if (g == 0) o.x = 0.0f;
        if (g == 33) o.w = 0.0f;
        sP4[r * SW4 + g] = o;
    }
    __syncthreads();

    if (!f_edge) {
        for (int i = tid; i < RV * 34; i += 256) {
            int r = i / 34, g = i - r * 34;
            const float4 p0 = sP4[r * SW4 + g];
            const float4 p1 = sP4[(r + 1) * SW4 + g];
            const float4 p2 = sP4[(r + 2) * SW4 + g];
            const float4 p3 = sP4[(r + 3) * SW4 + g];
            const float4 p4 = sP4[(r + 4) * SW4 + g];
            sV4[r * SW4 + g] = blur5v(p0, p4, p1, p3, p2);
        }
    } else {
        for (int i = tid; i < RV * 34; i += 256) {
            int r = i / 34, g = i - r * 34;
            const int gf = f0 - 1 + r;
            const int r0 = reflectF(gf - 2) - (f0 - 3);
            const int r1 = reflectF(gf - 1) - (f0 - 3);
            const int r2 = gf - (f0 - 3);
            const int r3 = reflectF(gf + 1) - (f0 - 3);
            const int r4 = reflectF(gf + 2) - (f0 - 3);
            const float4 p0 = sP4[r0 * SW4 + g];
            const float4 p1 = sP4[r1 * SW4 + g];
            const float4 p2 = sP4[r2 * SW4 + g];
            const float4 p3 = sP4[r3 * SW4 + g];
            const float4 p4 = sP4[r4 * SW4 + g];
            sV4[r * SW4 + g] = blur5v(p0, p4, p1, p3, p2);
        }
    }
    __syncthreads();

    for (int i = tid; i < RV * 32; i += 256) {
        int r = i >> 5, g = 1 + (i & 31);
        const float4 A = sV4[r * SW4 + g - 1];
        const float4 B = sV4[r * SW4 + g];
        const float4 C = sV4[r * SW4 + g + 1];
        float4 o;
        o.x = blur5(A.z, B.z, A.w, B.y, B.x);
        o.y = blur5(A.w, B.w, B.x, B.z, B.y);
        o.z = blur5(B.x, C.x, B.y, B.w, B.z);
        o.w = blur5(B.y, C.y, B.z, C.x, B.w);
        if (t_lo && g == 1) {
            o.x = blur5(B.z, B.z, B.y, B.y, B.x);
            o.y = blur5(B.y, B.w, B.x, B.z, B.y);
        }
        if (t_hi && g == 32) {
            o.z = blur5(B.x, B.z, B.y, B.w, B.z);
            o.w = blur5(B.y, B.y, B.z, B.z, B.w);
        }
        if ((f_lo && r == 0) || (f_hi && r == 17)) o = make_float4(NEG, NEG, NEG, NEG);
        sB4[r * SW4 + g] = o;
    }
    for (int i = tid; i < RV * 2; i += 256) {
        int r = i >> 1;
        int hi = i & 1;
        int s = hi ? 132 : 3;
        const float* vr = sV + r * SW;
        float v = blur5(vr[s - 2], vr[s + 2], vr[s - 1], vr[s + 1], vr[s]);
        if ((hi ? t_hi : t_lo) || (f_lo && r == 0) || (f_hi && r == 17)) v = NEG;
        sB[r * SW + s] = v;
    }
    __syncthreads();
}

struct Win8 {
    float c[8], l[8], rr[8], u[8], d[8];
};
__device__ __forceinline__ void load_win8(const float4* sB4, int r, int m, Win8& w) {
    const int g = 1 + 2 * m;
    const float4 Cm = sB4[(r + 1) * SW4 + g - 1];
    const float4 C0 = sB4[(r + 1) * SW4 + g];
    const float4 C1 = sB4[(r + 1) * SW4 + g + 1];
    const float4 C2 = sB4[(r + 1) * SW4 + g + 2];
    const float4 U0 = sB4[r * SW4 + g];
    const float4 U1 = sB4[r * SW4 + g + 1];
    const float4 D0 = sB4[(r + 2) * SW4 + g];
    const float4 D1 = sB4[(r + 2) * SW4 + g + 1];
    w.c[0] = C0.x; w.c[1] = C0.y; w.c[2] = C0.z; w.c[3] = C0.w;
    w.c[4] = C1.x; w.c[5] = C1.y; w.c[6] = C1.z; w.c[7] = C1.w;
    w.l[0] = Cm.w; w.l[1] = C0.x; w.l[2] = C0.y; w.l[3] = C0.z;
    w.l[4] = C0.w; w.l[5] = C1.x; w.l[6] = C1.y; w.l[7] = C1.z;
    w.rr[0] = C0.y; w.rr[1] = C0.z; w.rr[2] = C0.w; w.rr[3] = C1.x;
    w.rr[4] = C1.y; w.rr[5] = C1.z; w.rr[6] = C1.w; w.rr[7] = C2.x;
    w.u[0] = U0.x; w.u[1] = U0.y; w.u[2] = U0.z; w.u[3] = U0.w;
    w.u[4] = U1.x; w.u[5] = U1.y; w.u[6] = U1.z; w.u[7] = U1.w;
    w.d[0] = D0.x; w.d[1] = D0.y; w.d[2] = D0.z; w.d[3] = D0.w;
    w.d[4] = D1.x; w.d[5] = D1.y; w.d[6] = D1.z; w.d[7] = D1.w;
}

// k_prefix: per-batch prefix sums; hosts the (never-taken in practice) guard:
// if mn2 != 0 the march counts used threshold 0 and must be redone with x > mn2.
__global__ __launch_bounds__(256) void k_prefix(const float* __restrict__ spec,
                                                unsigned* __restrict__ mm,
                                                int* __restrict__ counts2,
                                                int* __restrict__ prefix2) {
    const int b = blockIdx.x;
    const int tid = threadIdx.x;
    const float mn2 = decf(mm[b * 4 + 2]);
    if (mn2 != 0.0f) {
        __shared__ __align__(16) float sR1[R1_WORDS];
        __shared__ __align__(16) float sR2[R2_WORDS];
        const float4* sB4 = (const float4*)sR2;
        const float mn = decf(mm[b * 4 + 0]);
        const float mx = decf(mm[b * 4 + 1]);
        const float rinv = 1.0f / (mx - mn);
        const float* sb_base = spec + (size_t)b * NF * NT;
        int* pcnt = (int*)sR1;
        for (int ty = 0; ty < NF / TF; ++ty)
        for (int tx = 0; tx < NT / TT; ++tx) {
            blur_tile(sb_base, ty * TF, tx * TT, mn, rinv, sR1, sR2, tid,
                      ty == 0, ty == NF / TF - 1, tx == 0, tx == NT / TT - 1);
            const int r = tid & 15, m = tid >> 4;
            Win8 w;
            load_win8(sB4, r, m, w);
            int cnt = 0;
#pragma unroll
            for (int k = 0; k < 8; k++) {
                float x = w.c[k];
                bool pk = (x >= w.l[k]) && (x >= w.rr[k]) && (x >= w.u[k]) && (x >= w.d[k]);
                cnt += (pk && (x > mn2)) ? 1 : 0;
            }
            (void)m;
            const int lane = tid & 63, wvv = tid >> 6;
            int cs = cnt;
            cs += __shfl_down(cs, 32);
            cs += __shfl_down(cs, 16);
            if (lane < 16) pcnt[wvv * 16 + lane] = cs;
            __syncthreads();
            if (tid < 16)
                counts2[(b * NF + ty * TF + tid) * 32 + tx] =
                    pcnt[tid] + pcnt[16 + tid] + pcnt[32 + tid] + pcnt[48 + tid];
            __syncthreads();
        }
    }
    const int* cb = counts2 + b * NF * 32;
    int* pb = prefix2 + b * NF * 32;
    int local[32];
    int s = 0;
    for (int c = 0; c < 32; c++) {
        local[c] = cb[tid * 32 + c];
        s += local[c];
    }
    __shared__ int tot[256];
    tot[tid] = s;
    __syncthreads();
    for (int off = 1; off < 256; off <<= 1) {
        int v = (tid >= off) ? tot[tid - off] : 0;
        __syncthreads();
        tot[tid] += v;
        __syncthreads();
    }
    int run = tot[tid] - s;
    for (int c = 0; c < 32; c++) {
        pb[tid * 32 + c] = run;
        run += local[c];
    }
}

__global__ __launch_bounds__(256) void k_extract(const float* __restrict__ spec, unsigned* __restrict__ mm,
                                                 const int* __restrict__ prefix2, float* __restrict__ out) {
    const int b = blockIdx.z;
    const int f0 = blockIdx.y * TF;
    const int t0 = blockIdx.x * TT;
    const int c0 = blockIdx.x;
    if (prefix2[(b * NF + f0) * 32 + c0] >= PAD_LEN) return;

    const int tid = threadIdx.x;
    __shared__ __align__(16) float sR1[R1_WORDS];
    __shared__ __align__(16) float sR2[R2_WORDS];
    const float4* sB4 = (const float4*)sR2;

    const float mn = decf(mm[b * 4 + 0]);
    const float mx = decf(mm[b * 4 + 1]);
    const float rinv = 1.0f / (mx - mn);
    const float mn2 = decf(mm[b * 4 + 2]);
    const float mx2 = decf(mm[b * 4 + 3]);
    const float rinv2 = 1.0f / (mx2 - mn2);
    const float* sb_base = spec + (size_t)b * NF * NT;

    const bool f_lo = (blockIdx.y == 0), f_hi = (blockIdx.y == NF / TF - 1);
    const bool t_lo = (blockIdx.x == 0), t_hi = (blockIdx.x == NT / TT - 1);
    blur_tile(sb_base, f0, t0, mn, rinv, sR1, sR2, tid, f_lo, f_hi, t_lo, t_hi);

    const int r = tid & 15, m = tid >> 4;
    const int gf = f0 + r;
    const int base = prefix2[(b * NF + gf) * 32 + c0];
    Win8 w;
    load_win8(sB4, r, m, w);
    bool pos[8];
    int mycnt = 0;
#pragma unroll
    for (int k = 0; k < 8; k++) {
        float x = w.c[k];
        pos[k] = (x >= w.l[k]) && (x >= w.rr[k]) && (x >= w.u[k]) && (x >= w.d[k]) && (x > mn2);
        mycnt += pos[k] ? 1 : 0;
    }
    const int lane = tid & 63, wv = tid >> 6, p = (tid >> 4) & 3;
    int s = mycnt;
    int t1 = __shfl_up(s, 16); if (p >= 1) s += t1;
    int t2 = __shfl_up(s, 32); if (p >= 2) s += t2;
    __shared__ int wtot[4][16];
    if (p == 3) wtot[wv][lane & 15] = s;
    __syncthreads();
    int woff = 0;
    for (int w2 = 0; w2 < wv; ++w2) woff += wtot[w2][r];
    int rank = base + woff + (s - mycnt);
#pragma unroll
    for (int k = 0; k < 8; k++) {
        if (pos[k]) {
            if (rank < PAD_LEN) {
                int gc = t0 + 8 * m + k;
                out[b * 768 + rank]       = (float)gf * (1.0f / 256.0f);
                out[b * 768 + 256 + rank] = (float)gc * (1.0f / 4096.0f);
                out[b * 768 + 512 + rank] = (w.c[k] - mn2) * rinv2;
            }
            rank++;
        }
    }
}

extern "C" void kernel_launch(void* const* d_in, const int* in_sizes, int n_in,
                              void* d_out, int out_size, void* d_ws, size_t ws_size,
                              hipStream_t stream) {
    const float* spec = (const float*)d_in[0];
    float* out = (float*)d_out;
    unsigned* mm = (unsigned*)((char*)d_ws + MM_OFF);
    int* counts2 = (int*)((char*)d_ws + CNT_OFF);
    int* prefix2 = (int*)((char*)d_ws + PFX_OFF);

    k_init<<<96, 256, 0, stream>>>(out, mm);
    k_minmax<<<dim3(64, NB), 256, 0, stream>>>(spec, mm);
    k_march<<<dim3(NSTRIP / 4, NB), 256, 0, stream>>>(spec, mm, counts2);
    k_prefix<<<NB, 256, 0, stream>>>(spec, mm, counts2, prefix2);
    dim3 tgrid(NT / TT, NF / TF, NB);
    k_extract<<<tgrid, 256, 0, stream>>>(spec, mm, prefix2, out);
}